// Round 5
// baseline (824.161 us; speedup 1.0000x reference)
//
#include <hip/hip_runtime.h>
#include <math.h>

#define BB 64
#define NN 207
#define TT 12
#define NC 10
#define NTOT (BB*NN*TT)     // 158976
#define NP 208              // padded matrix dim (pad row 207: identity)
#define TRI8 21736          // 208*209/2 packed lower triangle
#define WST 209             // W row stride (odd -> full bank spread)
#define PTS 272             // Pt row stride (rows k1..207 + 64 W rows at 208..271)
#define KDT 1024            // kD block size: 16 waves to hide LDS/dep latency

// ws layout (float offsets). Total ~437,879 floats = 1.75 MB.
#define KS_OFF   0          // [C][N][N]       428490
#define DT_OFF   428490     // [C][T]          120
#define UT_OFF   428610     // [C][T][T]       1440
#define ULOG_OFF 430050     // [C]             10
#define VLOG_OFF 430060     // [C]             10
#define CNT_OFF  430070     // int completion counter (zeroed by k1)
#define MAEC_OFF 430071     // [64] mask-count slots (no atomics, slot per block)
#define MAEA_OFF 430135     // [64] abs-sum slots
#define SSQ_OFF  430199     // [C][T][B]       7680

// compiler ordering fence for intra-wave LDS sequencing (HW: same-wave LDS ops
// execute in order; this only stops compile-time reordering/caching)
__device__ __forceinline__ void WB() {
    __builtin_amdgcn_wave_barrier();
    __asm__ volatile("" ::: "memory");
}

// round-robin tournament pairing: 12 players, 11 rounds, 6 disjoint pairs/round
__device__ inline void jpair(int r, int pi, int& p, int& q) {
    if (pi == 0) { p = 11; q = r % 11; }
    else { p = (r + pi) % 11; q = (r + 11 - pi) % 11; }
}

// k1 (640 thr): blocks 0..129 tiled Ks = Ls*Ls^T; block 130 = 10 wave-parallel
// BARRIER-FREE 12x12 Jacobi eigh (one wave per component; intra-wave LDS is
// in-order so no __syncthreads on the 77-round serial chain) + logdets +
// counter zero; blocks 131..194 = slot-based masked-MAE partials.
__global__ __launch_bounds__(640) void k1(const float* __restrict__ Ls,
                                          const float* __restrict__ Lt,
                                          const float* __restrict__ mu,
                                          const float* __restrict__ tg,
                                          const float* __restrict__ uns,
                                          float* __restrict__ ws) {
    __shared__ float sh[3520];
    int t = threadIdx.x;
    int blk = blockIdx.x;
    if (blk < 130) {
        int c = blk / 13, it = blk % 13, i0 = it * 16;
        float* At = sh;   // [207][16] stride 17
        for (int u = t; u < 16*NN; u += 640) {
            int k = u % NN, ii = u / NN;
            int r = i0 + ii;
            At[k*17 + ii] = (r < NN) ? Ls[(size_t)(c*NN + r)*NN + k] : 0.f;
        }
        __syncthreads();
        int j = t;
        if (j < NN) {
            float acc[16];
            #pragma unroll
            for (int ii = 0; ii < 16; ++ii) acc[ii] = 0.f;
            const float* lsr = Ls + (size_t)(c*NN + j)*NN;
            int kb = i0 + 15; if (j < kb) kb = j;   // tril
            for (int k = 0; k <= kb; ++k) {
                float g = lsr[k];
                const float* ar = At + k*17;
                #pragma unroll
                for (int ii = 0; ii < 16; ++ii) acc[ii] += g * ar[ii];
            }
            float* ksb = ws + KS_OFF + (size_t)c*NN*NN;
            #pragma unroll
            for (int ii = 0; ii < 16; ++ii) {
                int r = i0 + ii;
                if (r < NN) ksb[(size_t)r*NN + j] = acc[ii];
            }
        }
    } else if (blk == 130) {
        int wv = t >> 6, l = t & 63;      // wave wv owns component wv
        float* A  = sh + wv*304;          // 12x12 working matrix
        float* V  = A + 144;              // eigenvectors
        float* rc = A + 288;              // 6 cos
        float* rs = A + 294;              // 6 sin
        for (int u = l; u < 144; u += 64) {
            int i = u / 12, j = u % 12;
            int kmax = (i < j) ? i : j;
            const float* a = Lt + wv*144 + i*12;
            const float* b = Lt + wv*144 + j*12;
            float s = 0.f;
            for (int k = 0; k <= kmax; ++k) s += a[k]*b[k];
            A[u] = s; V[u] = (i == j) ? 1.f : 0.f;
        }
        WB();
        for (int sweep = 0; sweep < 7; ++sweep)
        for (int r = 0; r < 11; ++r) {
            if (l < 6) {
                int p, q; jpair(r, l, p, q);
                float app = A[p*13], aqq = A[q*13], apq = A[p*12 + q];
                float cs = 1.f, sn = 0.f;
                if (fabsf(apq) > 1e-30f) {
                    float tau = (aqq - app) / (2.f * apq);
                    float t2 = ((tau >= 0.f) ? 1.f : -1.f) / (fabsf(tau) + sqrtf(1.f + tau*tau));
                    cs = 1.f / sqrtf(1.f + t2*t2);
                    sn = t2 * cs;
                }
                rc[l] = cs; rs[l] = sn;
            }
            WB();
            for (int u = l; u < 72; u += 64) {        // rows p,q
                int pi = u / 12, k = u % 12, p, q;
                jpair(r, pi, p, q);
                float cs = rc[pi], sn = rs[pi];
                float x = A[p*12 + k], y = A[q*12 + k];
                A[p*12 + k] = cs*x - sn*y;
                A[q*12 + k] = sn*x + cs*y;
            }
            WB();
            for (int u = l; u < 144; u += 64) {       // cols + V
                int isV = (u >= 72);
                int v2 = isV ? u - 72 : u;
                int pi = v2 / 12, i = v2 % 12, p, q;
                jpair(r, pi, p, q);
                float cs = rc[pi], sn = rs[pi];
                float* M = isV ? V : A;
                float x = M[i*12 + p], y = M[i*12 + q];
                M[i*12 + p] = cs*x - sn*y;
                M[i*12 + q] = sn*x + cs*y;
            }
            WB();
        }
        if (l < 12) ws[DT_OFF + wv*12 + l] = A[l*13];
        for (int u = l; u < 144; u += 64) ws[UT_OFF + wv*144 + u] = V[u];
        float su = 0.f;
        for (int i = l; i < NN; i += 64) su += logf(Ls[(size_t)(wv*NN + i)*NN + i]);
        for (int o = 32; o; o >>= 1) su += __shfl_down(su, o, 64);
        if (l == 0) ws[ULOG_OFF + wv] = su;
        float sv = (l < 12) ? logf(Lt[wv*144 + l*13]) : 0.f;
        for (int o = 32; o; o >>= 1) sv += __shfl_down(sv, o, 64);
        if (l == 0) ws[VLOG_OFF + wv] = sv;
        if (t == 0) *((int*)(ws + CNT_OFF)) = 0;
    } else {
        int mb = blk - 131;               // 64 MAE blocks, 2484 elems each
        int base = mb * 2484;
        float mk = 0.f, dd = 0.f;
        for (int u = base + t; u < base + 2484; u += 640) {
            float m2 = (uns[u] != 0.f) ? 1.f : 0.f;
            mk += m2;
            dd += fabsf(mu[u] - tg[u]) * m2;
        }
        for (int o = 32; o; o >>= 1) {
            mk += __shfl_down(mk, o, 64);
            dd += __shfl_down(dd, o, 64);
        }
        int wv = t >> 6, l = t & 63;
        if (l == 0) { sh[wv] = mk; sh[16 + wv] = dd; }
        __syncthreads();
        if (t == 0) {
            float a = 0.f, b2 = 0.f;
            for (int q = 0; q < 10; ++q) { a += sh[q]; b2 += sh[16 + q]; }
            ws[MAEC_OFF + mb] = a;
            ws[MAEA_OFF + mb] = b2;
        }
    }
}

// kD: blocked (P=16) Cholesky of A = Dt[c,j]*Ks_c + sig^2 I fused with forward
// substitution (64 RHS as trapezoid rows) + inline Y-transform + last-block
// logsumexp epilogue. amdgpu_waves_per_eu(4,4): pins the allocator's occupancy
// TARGET (not just the cap, which launch_bounds(,4) set in R4 to no effect) to
// 4 waves/EU -> 128-VGPR budget -> no scratch spill at 1024 threads.
__global__ __launch_bounds__(KDT)
__attribute__((amdgpu_waves_per_eu(4, 4)))
void kD(const float* __restrict__ sig,
        const float* __restrict__ mu,
        const float* __restrict__ tg,
        const float* __restrict__ wgt,
        float* __restrict__ ws,
        float* __restrict__ out) {
    extern __shared__ float lds[];
    float* Apk = lds;                    // 21736
    float* W   = Apk + TRI8;             // 64*209 = 13376
    float* Pt  = W + 64*WST;             // 16*272 + 64 slack = 4416
    float* ldg = Pt + 16*PTS + 64;       // 256 (diag block L, row-major)
    float* dnv = ldg + 256;              // 16  (1/L[kk][kk])
    float* utl = dnv + 16;               // 12  (Ut[c][:,j])
    __shared__ int lflag;
    int t = threadIdx.x;
    int c = blockIdx.x / TT, jj = blockIdx.x % TT;
    float dt = ws[DT_OFF + blockIdx.x];
    float sg = sig[c], sg2 = sg*sg;
    const float* KsC = ws + KS_OFF + (size_t)c*NN*NN;

    if (t < 12) utl[t] = ws[UT_OFF + c*144 + t*12 + jj];
    for (int f = t; f < TRI8; f += KDT) {
        int i = (int)((sqrtf(8.f*(float)f + 1.f) - 1.f)*0.5f);
        while ((i+1)*(i+2)/2 <= f) ++i;
        while (i*(i+1)/2 > f) --i;
        int j2 = f - i*(i+1)/2;
        float v;
        if (i == NN) v = (j2 == NN) ? 1.f : 0.f;
        else { v = dt * KsC[i*NN + j2]; if (i == j2) v += sg2; }
        Apk[f] = v;
    }
    __syncthreads();
    // inline Y-transform: W[b][i] = sum_q (tg-mu)[b,i,q] * Ut[c][q][jj]
    for (int u = t; u < 64*NN; u += KDT) {
        int b = u / NN, i = u - b*NN;
        const float* mp = mu + (size_t)(b*NN + i)*TT;
        const float* tp = tg + (size_t)(b*NN + i)*TT;
        float s = 0.f;
        #pragma unroll
        for (int q = 0; q < TT; ++q) s += (tp[q] - mp[q]) * utl[q];
        W[b*WST + i] = s;
    }
    if (t < 64) W[t*WST + NN] = 0.f;
    __syncthreads();

    for (int p = 0; p < 13; ++p) {
        int k0 = p*16, k1 = k0 + 16;
        // ---- 16x16 diag factor, wave 0, registers + shuffles
        if (t < 64) {
            int r = t;
            int rr = (r < 16) ? (k0 + r) : k0;
            int base = ((rr*(rr+1)) >> 1) + k0;
            float a[16];
            #pragma unroll
            for (int m = 0; m < 16; ++m) a[m] = Apk[base + m];
            #pragma unroll
            for (int kk = 0; kk < 16; ++kk) {
                float d = __shfl(a[kk], kk);
                float dv = 1.0f / sqrtf(d);
                if (t == 0) dnv[kk] = dv;
                if (r < 16 && r > kk) a[kk] *= dv;
                #pragma unroll
                for (int j2 = kk+1; j2 < 16; ++j2) {
                    float v = __shfl(a[kk], j2);
                    if (r < 16 && r > kk && j2 <= r) a[j2] -= a[kk]*v;
                }
            }
            if (r < 16) {
                #pragma unroll
                for (int m = 0; m < 16; ++m) ldg[r*16 + m] = a[m];
            }
        }
        __syncthreads();
        // ---- unified panel row solve: below-A rows (incl pad) + 64 W rows
        int nA = NP - k1;
        int nsolve = nA + 64;
        if (t < nsolve) {
            bool isW = (t >= nA);
            float arow[16];
            int abase = 0, wb = 0;
            if (!isW) {
                int r = k1 + t;
                abase = ((r*(r+1)) >> 1) + k0;
                #pragma unroll
                for (int m = 0; m < 16; ++m) arow[m] = Apk[abase + m];
            } else {
                wb = t - nA;
                #pragma unroll
                for (int m = 0; m < 16; ++m) arow[m] = W[wb*WST + k0 + m];
            }
            #pragma unroll
            for (int kk = 0; kk < 16; ++kk) {
                float x = arow[kk];
                #pragma unroll
                for (int m = 0; m < kk; ++m) x -= arow[m] * ldg[kk*16 + m];
                arow[kk] = x * dnv[kk];
            }
            int rho = isW ? (NP + wb) : (k1 + t);
            if (!isW) {
                #pragma unroll
                for (int m = 0; m < 16; ++m) Apk[abase + m] = arow[m];
            } else {
                #pragma unroll
                for (int m = 0; m < 16; ++m) W[wb*WST + k0 + m] = arow[m];
            }
            #pragma unroll
            for (int m = 0; m < 16; ++m) Pt[m*PTS + rho] = arow[m];
        }
        __syncthreads();
        // ---- trailing rank-16 update, 128x128 tiles, 4x4 microtiles
        int nc2 = NP - k1;
        int nr2 = nc2 + 64;
        if (nc2 > 0) {
            int ty = t >> 5, tx = t & 31;
            for (int rg = 0; rg < nr2; rg += 128) {
                int rbase = k1 + rg + 4*ty;
                if (rbase >= NP + 64) continue;
                for (int cg = 0; cg < nc2; cg += 128) {
                    int cbase = k1 + cg + 4*tx;
                    if (cbase >= NP) continue;
                    if (rbase + 3 < cbase && rbase + 3 < NP) continue;
                    float acc[4][4];
                    #pragma unroll
                    for (int a2 = 0; a2 < 4; ++a2)
                        #pragma unroll
                        for (int b2 = 0; b2 < 4; ++b2) acc[a2][b2] = 0.f;
                    #pragma unroll
                    for (int kk = 0; kk < 16; ++kk) {
                        float4 av = *(const float4*)(Pt + kk*PTS + rbase);
                        float4 bv = *(const float4*)(Pt + kk*PTS + cbase);
                        acc[0][0] += av.x*bv.x; acc[0][1] += av.x*bv.y;
                        acc[0][2] += av.x*bv.z; acc[0][3] += av.x*bv.w;
                        acc[1][0] += av.y*bv.x; acc[1][1] += av.y*bv.y;
                        acc[1][2] += av.y*bv.z; acc[1][3] += av.y*bv.w;
                        acc[2][0] += av.z*bv.x; acc[2][1] += av.z*bv.y;
                        acc[2][2] += av.z*bv.z; acc[2][3] += av.z*bv.w;
                        acc[3][0] += av.w*bv.x; acc[3][1] += av.w*bv.y;
                        acc[3][2] += av.w*bv.z; acc[3][3] += av.w*bv.w;
                    }
                    #pragma unroll
                    for (int ri2 = 0; ri2 < 4; ++ri2) {
                        int rho = rbase + ri2;
                        if (rho >= NP + 64) continue;
                        #pragma unroll
                        for (int ci2 = 0; ci2 < 4; ++ci2) {
                            int jc = cbase + ci2;
                            if (jc >= NP) continue;
                            if (rho < NP) {
                                if (jc <= rho)
                                    Apk[((rho*(rho+1))>>1) + jc] -= acc[ri2][ci2];
                            } else {
                                W[(rho - NP)*WST + jc] -= acc[ri2][ci2];
                            }
                        }
                    }
                }
            }
        }
        __syncthreads();
    }
    // quad = ||L^-1 y||^2 per batch
    {
        int b = t >> 4, seg = t & 15;
        float part = 0.f;
        int ks = seg * 13;
        for (int k = ks; k < ks + 13; ++k) { float z = W[b*WST + k]; part += z*z; }
        part += __shfl_down(part, 8, 16);
        part += __shfl_down(part, 4, 16);
        part += __shfl_down(part, 2, 16);
        part += __shfl_down(part, 1, 16);
        if (seg == 0) ws[SSQ_OFF + (blockIdx.x << 6) + b] = part;
    }
    // last-block epilogue (device-scope release/acquire via fence+atomic)
    __threadfence();
    __syncthreads();
    if (t == 0) {
        int old = atomicAdd((int*)(ws + CNT_OFF), 1);
        lflag = (old == NC*TT - 1) ? 1 : 0;
    }
    __syncthreads();
    if (!lflag) return;
    __threadfence();
    float* ep = Apk;            // reuse LDS: 640 ll values + 64 nll
    float* nl = Apk + 640;
    const float C0 = -0.5f * 2484.0f * 1.8378770664093453f;
    for (int u = t; u < 640; u += KDT) {
        int b2 = u / NC, cc = u % NC;
        float q = 0.f;
        for (int j2 = 0; j2 < TT; ++j2) q += ws[SSQ_OFF + (cc*TT + j2)*64 + b2];
        ep[u] = C0 - 0.5f*q + 207.f*ws[VLOG_OFF + cc] + 12.f*ws[ULOG_OFF + cc]
                + logf(wgt[b2*NC + cc]);
    }
    __syncthreads();
    if (t < 64) {
        float mx = -1e30f;
        for (int cc = 0; cc < NC; ++cc) mx = fmaxf(mx, ep[t*NC + cc]);
        float s = 0.f;
        for (int cc = 0; cc < NC; ++cc) s += expf(ep[t*NC + cc] - mx);
        nl[t] = -(mx + logf(s));
    }
    __syncthreads();
    if (t < 64) {
        float v = nl[t];
        for (int o = 32; o; o >>= 1) v += __shfl_down(v, o, 64);
        if (t == 0) {
            float sm = 0.f, sa = 0.f;
            for (int q2 = 0; q2 < 64; ++q2) {
                sm += ws[MAEC_OFF + q2];
                sa += ws[MAEA_OFF + q2];
            }
            float mse = (sm > 0.f) ? sa / sm : 0.f;
            out[0] = 0.1f * (v * (1.f/64.f)) + 0.9f * mse;
        }
    }
}

extern "C" void kernel_launch(void* const* d_in, const int* in_sizes, int n_in,
                              void* d_out, int out_size, void* d_ws, size_t ws_size,
                              hipStream_t stream) {
    const float* mu  = (const float*)d_in[0];
    const float* tg  = (const float*)d_in[1];
    const float* uns = (const float*)d_in[2];
    const float* wgt = (const float*)d_in[3];
    const float* sig = (const float*)d_in[4];
    // d_in[5] = R, unused by the reference loss
    const float* Ls  = (const float*)d_in[6];
    const float* Lt  = (const float*)d_in[7];
    float* out = (float*)d_out;
    float* ws  = (float*)d_ws;

    const int kd_lds = (TRI8 + 64*WST + 16*PTS + 64 + 256 + 16 + 12) * 4; // 159,248 B
    (void)hipFuncSetAttribute((const void*)kD,
                              hipFuncAttributeMaxDynamicSharedMemorySize, kd_lds);

    k1<<<195, 640, 0, stream>>>(Ls, Lt, mu, tg, uns, ws);
    kD<<<NC*TT, KDT, kd_lds, stream>>>(sig, mu, tg, wgt, ws, out);
}

// Round 6
// 511.263 us; speedup vs baseline: 1.6120x; 1.6120x over previous
//
#include <hip/hip_runtime.h>
#include <math.h>

#define BB 64
#define NN 207
#define TT 12
#define NC 10
#define NTOT (BB*NN*TT)     // 158976
#define NP 208              // padded matrix dim (pad row 207: identity)
#define TRI8 21736          // 208*209/2 packed lower triangle
#define WST 209             // W row stride (odd -> full bank spread)
#define PTS 272             // Pt row stride (rows k1..207 + 64 W rows at 208..271)
#define KDT 512             // kD block size: 8 waves/CU (1 block/CU via LDS).
                            // 512 chosen so the allocator's occupancy heuristic
                            // (2 wg/CU -> 4 waves/EU) budgets 128 VGPR > ~96
                            // demand. 1024 threads forced a 64-VGPR budget ->
                            // ~330 MB scratch spill (R3-R5, WRITE_SIZE counter).

// ws layout (float offsets). Total ~437,879 floats = 1.75 MB.
#define KS_OFF   0          // [C][N][N]       428490
#define DT_OFF   428490     // [C][T]          120
#define UT_OFF   428610     // [C][T][T]       1440
#define ULOG_OFF 430050     // [C]             10
#define VLOG_OFF 430060     // [C]             10
#define CNT_OFF  430070     // int completion counter (zeroed by k1)
#define MAEC_OFF 430071     // [64] mask-count slots (no atomics, slot per block)
#define MAEA_OFF 430135     // [64] abs-sum slots
#define SSQ_OFF  430199     // [C][T][B]       7680

// compiler ordering fence for intra-wave LDS sequencing (HW: same-wave LDS ops
// execute in order; this only stops compile-time reordering/caching)
__device__ __forceinline__ void WB() {
    __builtin_amdgcn_wave_barrier();
    __asm__ volatile("" ::: "memory");
}

// round-robin tournament pairing: 12 players, 11 rounds, 6 disjoint pairs/round
__device__ inline void jpair(int r, int pi, int& p, int& q) {
    if (pi == 0) { p = 11; q = r % 11; }
    else { p = (r + pi) % 11; q = (r + 11 - pi) % 11; }
}

// k1 (640 thr): blocks 0..129 tiled Ks = Ls*Ls^T; block 130 = 10 wave-parallel
// barrier-free 12x12 Jacobi eigh + logdets + counter zero; blocks 131..194 =
// slot-based masked-MAE partials.
__global__ __launch_bounds__(640) void k1(const float* __restrict__ Ls,
                                          const float* __restrict__ Lt,
                                          const float* __restrict__ mu,
                                          const float* __restrict__ tg,
                                          const float* __restrict__ uns,
                                          float* __restrict__ ws) {
    __shared__ float sh[3520];
    int t = threadIdx.x;
    int blk = blockIdx.x;
    if (blk < 130) {
        int c = blk / 13, it = blk % 13, i0 = it * 16;
        float* At = sh;   // [207][16] stride 17
        for (int u = t; u < 16*NN; u += 640) {
            int k = u % NN, ii = u / NN;
            int r = i0 + ii;
            At[k*17 + ii] = (r < NN) ? Ls[(size_t)(c*NN + r)*NN + k] : 0.f;
        }
        __syncthreads();
        int j = t;
        if (j < NN) {
            float acc[16];
            #pragma unroll
            for (int ii = 0; ii < 16; ++ii) acc[ii] = 0.f;
            const float* lsr = Ls + (size_t)(c*NN + j)*NN;
            int kb = i0 + 15; if (j < kb) kb = j;   // tril
            for (int k = 0; k <= kb; ++k) {
                float g = lsr[k];
                const float* ar = At + k*17;
                #pragma unroll
                for (int ii = 0; ii < 16; ++ii) acc[ii] += g * ar[ii];
            }
            float* ksb = ws + KS_OFF + (size_t)c*NN*NN;
            #pragma unroll
            for (int ii = 0; ii < 16; ++ii) {
                int r = i0 + ii;
                if (r < NN) ksb[(size_t)r*NN + j] = acc[ii];
            }
        }
    } else if (blk == 130) {
        int wv = t >> 6, l = t & 63;      // wave wv owns component wv
        float* A  = sh + wv*304;          // 12x12 working matrix
        float* V  = A + 144;              // eigenvectors
        float* rc = A + 288;              // 6 cos
        float* rs = A + 294;              // 6 sin
        for (int u = l; u < 144; u += 64) {
            int i = u / 12, j = u % 12;
            int kmax = (i < j) ? i : j;
            const float* a = Lt + wv*144 + i*12;
            const float* b = Lt + wv*144 + j*12;
            float s = 0.f;
            for (int k = 0; k <= kmax; ++k) s += a[k]*b[k];
            A[u] = s; V[u] = (i == j) ? 1.f : 0.f;
        }
        WB();
        for (int sweep = 0; sweep < 7; ++sweep)
        for (int r = 0; r < 11; ++r) {
            if (l < 6) {
                int p, q; jpair(r, l, p, q);
                float app = A[p*13], aqq = A[q*13], apq = A[p*12 + q];
                float cs = 1.f, sn = 0.f;
                if (fabsf(apq) > 1e-30f) {
                    float tau = (aqq - app) / (2.f * apq);
                    float t2 = ((tau >= 0.f) ? 1.f : -1.f) / (fabsf(tau) + sqrtf(1.f + tau*tau));
                    cs = 1.f / sqrtf(1.f + t2*t2);
                    sn = t2 * cs;
                }
                rc[l] = cs; rs[l] = sn;
            }
            WB();
            for (int u = l; u < 72; u += 64) {        // rows p,q
                int pi = u / 12, k = u % 12, p, q;
                jpair(r, pi, p, q);
                float cs = rc[pi], sn = rs[pi];
                float x = A[p*12 + k], y = A[q*12 + k];
                A[p*12 + k] = cs*x - sn*y;
                A[q*12 + k] = sn*x + cs*y;
            }
            WB();
            for (int u = l; u < 144; u += 64) {       // cols + V
                int isV = (u >= 72);
                int v2 = isV ? u - 72 : u;
                int pi = v2 / 12, i = v2 % 12, p, q;
                jpair(r, pi, p, q);
                float cs = rc[pi], sn = rs[pi];
                float* M = isV ? V : A;
                float x = M[i*12 + p], y = M[i*12 + q];
                M[i*12 + p] = cs*x - sn*y;
                M[i*12 + q] = sn*x + cs*y;
            }
            WB();
        }
        if (l < 12) ws[DT_OFF + wv*12 + l] = A[l*13];
        for (int u = l; u < 144; u += 64) ws[UT_OFF + wv*144 + u] = V[u];
        float su = 0.f;
        for (int i = l; i < NN; i += 64) su += logf(Ls[(size_t)(wv*NN + i)*NN + i]);
        for (int o = 32; o; o >>= 1) su += __shfl_down(su, o, 64);
        if (l == 0) ws[ULOG_OFF + wv] = su;
        float sv = (l < 12) ? logf(Lt[wv*144 + l*13]) : 0.f;
        for (int o = 32; o; o >>= 1) sv += __shfl_down(sv, o, 64);
        if (l == 0) ws[VLOG_OFF + wv] = sv;
        if (t == 0) *((int*)(ws + CNT_OFF)) = 0;
    } else {
        int mb = blk - 131;               // 64 MAE blocks, 2484 elems each
        int base = mb * 2484;
        float mk = 0.f, dd = 0.f;
        for (int u = base + t; u < base + 2484; u += 640) {
            float m2 = (uns[u] != 0.f) ? 1.f : 0.f;
            mk += m2;
            dd += fabsf(mu[u] - tg[u]) * m2;
        }
        for (int o = 32; o; o >>= 1) {
            mk += __shfl_down(mk, o, 64);
            dd += __shfl_down(dd, o, 64);
        }
        int wv = t >> 6, l = t & 63;
        if (l == 0) { sh[wv] = mk; sh[16 + wv] = dd; }
        __syncthreads();
        if (t == 0) {
            float a = 0.f, b2 = 0.f;
            for (int q = 0; q < 10; ++q) { a += sh[q]; b2 += sh[16 + q]; }
            ws[MAEC_OFF + mb] = a;
            ws[MAEA_OFF + mb] = b2;
        }
    }
}

// kD: blocked (P=16) Cholesky of A = Dt[c,j]*Ks_c + sig^2 I fused with forward
// substitution (64 RHS as trapezoid rows) + inline Y-transform + last-block
// logsumexp epilogue. 512 threads (see KDT comment).
__global__ __launch_bounds__(KDT)
__attribute__((amdgpu_waves_per_eu(2, 2)))
void kD(const float* __restrict__ sig,
        const float* __restrict__ mu,
        const float* __restrict__ tg,
        const float* __restrict__ wgt,
        float* __restrict__ ws,
        float* __restrict__ out) {
    extern __shared__ float lds[];
    float* Apk = lds;                    // 21736
    float* W   = Apk + TRI8;             // 64*209 = 13376
    float* Pt  = W + 64*WST;             // 16*272 + 64 slack = 4416
    float* ldg = Pt + 16*PTS + 64;       // 256 (diag block L, row-major)
    float* dnv = ldg + 256;              // 16  (1/L[kk][kk])
    float* utl = dnv + 16;               // 12  (Ut[c][:,j])
    __shared__ int lflag;
    int t = threadIdx.x;
    int c = blockIdx.x / TT, jj = blockIdx.x % TT;
    float dt = ws[DT_OFF + blockIdx.x];
    float sg = sig[c], sg2 = sg*sg;
    const float* KsC = ws + KS_OFF + (size_t)c*NN*NN;

    if (t < 12) utl[t] = ws[UT_OFF + c*144 + t*12 + jj];
    for (int f = t; f < TRI8; f += KDT) {
        int i = (int)((sqrtf(8.f*(float)f + 1.f) - 1.f)*0.5f);
        while ((i+1)*(i+2)/2 <= f) ++i;
        while (i*(i+1)/2 > f) --i;
        int j2 = f - i*(i+1)/2;
        float v;
        if (i == NN) v = (j2 == NN) ? 1.f : 0.f;
        else { v = dt * KsC[i*NN + j2]; if (i == j2) v += sg2; }
        Apk[f] = v;
    }
    __syncthreads();
    // inline Y-transform: W[b][i] = sum_q (tg-mu)[b,i,q] * Ut[c][q][jj]
    for (int u = t; u < 64*NN; u += KDT) {
        int b = u / NN, i = u - b*NN;
        const float* mp = mu + (size_t)(b*NN + i)*TT;
        const float* tp = tg + (size_t)(b*NN + i)*TT;
        float s = 0.f;
        #pragma unroll
        for (int q = 0; q < TT; ++q) s += (tp[q] - mp[q]) * utl[q];
        W[b*WST + i] = s;
    }
    if (t < 64) W[t*WST + NN] = 0.f;
    __syncthreads();

    for (int p = 0; p < 13; ++p) {
        int k0 = p*16, k1 = k0 + 16;
        // ---- 16x16 diag factor, wave 0, registers + shuffles
        if (t < 64) {
            int r = t;
            int rr = (r < 16) ? (k0 + r) : k0;
            int base = ((rr*(rr+1)) >> 1) + k0;
            float a[16];
            #pragma unroll
            for (int m = 0; m < 16; ++m) a[m] = Apk[base + m];
            #pragma unroll
            for (int kk = 0; kk < 16; ++kk) {
                float d = __shfl(a[kk], kk);
                float dv = 1.0f / sqrtf(d);
                if (t == 0) dnv[kk] = dv;
                if (r < 16 && r > kk) a[kk] *= dv;
                #pragma unroll
                for (int j2 = kk+1; j2 < 16; ++j2) {
                    float v = __shfl(a[kk], j2);
                    if (r < 16 && r > kk && j2 <= r) a[j2] -= a[kk]*v;
                }
            }
            if (r < 16) {
                #pragma unroll
                for (int m = 0; m < 16; ++m) ldg[r*16 + m] = a[m];
            }
        }
        __syncthreads();
        // ---- unified panel row solve: below-A rows (incl pad) + 64 W rows
        int nA = NP - k1;
        int nsolve = nA + 64;
        if (t < nsolve) {
            bool isW = (t >= nA);
            float arow[16];
            int abase = 0, wb = 0;
            if (!isW) {
                int r = k1 + t;
                abase = ((r*(r+1)) >> 1) + k0;
                #pragma unroll
                for (int m = 0; m < 16; ++m) arow[m] = Apk[abase + m];
            } else {
                wb = t - nA;
                #pragma unroll
                for (int m = 0; m < 16; ++m) arow[m] = W[wb*WST + k0 + m];
            }
            #pragma unroll
            for (int kk = 0; kk < 16; ++kk) {
                float x = arow[kk];
                #pragma unroll
                for (int m = 0; m < kk; ++m) x -= arow[m] * ldg[kk*16 + m];
                arow[kk] = x * dnv[kk];
            }
            int rho = isW ? (NP + wb) : (k1 + t);
            if (!isW) {
                #pragma unroll
                for (int m = 0; m < 16; ++m) Apk[abase + m] = arow[m];
            } else {
                #pragma unroll
                for (int m = 0; m < 16; ++m) W[wb*WST + k0 + m] = arow[m];
            }
            #pragma unroll
            for (int m = 0; m < 16; ++m) Pt[m*PTS + rho] = arow[m];
        }
        __syncthreads();
        // ---- trailing rank-16 update, 64x128 thread tile, 4x4 microtiles
        int nc2 = NP - k1;
        int nr2 = nc2 + 64;
        if (nc2 > 0) {
            int ty = t >> 5, tx = t & 31;     // 16 x 32 threads
            for (int rg = 0; rg < nr2; rg += 64) {
                int rbase = k1 + rg + 4*ty;
                if (rbase >= NP + 64) continue;
                for (int cg = 0; cg < nc2; cg += 128) {
                    int cbase = k1 + cg + 4*tx;
                    if (cbase >= NP) continue;
                    if (rbase + 3 < cbase && rbase + 3 < NP) continue;
                    float acc[4][4];
                    #pragma unroll
                    for (int a2 = 0; a2 < 4; ++a2)
                        #pragma unroll
                        for (int b2 = 0; b2 < 4; ++b2) acc[a2][b2] = 0.f;
                    #pragma unroll
                    for (int kk = 0; kk < 16; ++kk) {
                        float4 av = *(const float4*)(Pt + kk*PTS + rbase);
                        float4 bv = *(const float4*)(Pt + kk*PTS + cbase);
                        acc[0][0] += av.x*bv.x; acc[0][1] += av.x*bv.y;
                        acc[0][2] += av.x*bv.z; acc[0][3] += av.x*bv.w;
                        acc[1][0] += av.y*bv.x; acc[1][1] += av.y*bv.y;
                        acc[1][2] += av.y*bv.z; acc[1][3] += av.y*bv.w;
                        acc[2][0] += av.z*bv.x; acc[2][1] += av.z*bv.y;
                        acc[2][2] += av.z*bv.z; acc[2][3] += av.z*bv.w;
                        acc[3][0] += av.w*bv.x; acc[3][1] += av.w*bv.y;
                        acc[3][2] += av.w*bv.z; acc[3][3] += av.w*bv.w;
                    }
                    #pragma unroll
                    for (int ri2 = 0; ri2 < 4; ++ri2) {
                        int rho = rbase + ri2;
                        if (rho >= NP + 64) continue;
                        #pragma unroll
                        for (int ci2 = 0; ci2 < 4; ++ci2) {
                            int jc = cbase + ci2;
                            if (jc >= NP) continue;
                            if (rho < NP) {
                                if (jc <= rho)
                                    Apk[((rho*(rho+1))>>1) + jc] -= acc[ri2][ci2];
                            } else {
                                W[(rho - NP)*WST + jc] -= acc[ri2][ci2];
                            }
                        }
                    }
                }
            }
        }
        __syncthreads();
    }
    // quad = ||L^-1 y||^2 per batch: 64 batches x 8 segments of 26
    {
        int b = t >> 3, seg = t & 7;
        float part = 0.f;
        int ks = seg * 26;
        for (int k = ks; k < ks + 26; ++k) { float z = W[b*WST + k]; part += z*z; }
        part += __shfl_down(part, 4, 8);
        part += __shfl_down(part, 2, 8);
        part += __shfl_down(part, 1, 8);
        if (seg == 0) ws[SSQ_OFF + (blockIdx.x << 6) + b] = part;
    }
    // last-block epilogue (device-scope release/acquire via fence+atomic)
    __threadfence();
    __syncthreads();
    if (t == 0) {
        int old = atomicAdd((int*)(ws + CNT_OFF), 1);
        lflag = (old == NC*TT - 1) ? 1 : 0;
    }
    __syncthreads();
    if (!lflag) return;
    __threadfence();
    float* ep = Apk;            // reuse LDS: 640 ll values + 64 nll
    float* nl = Apk + 640;
    const float C0 = -0.5f * 2484.0f * 1.8378770664093453f;
    for (int u = t; u < 640; u += KDT) {
        int b2 = u / NC, cc = u % NC;
        float q = 0.f;
        for (int j2 = 0; j2 < TT; ++j2) q += ws[SSQ_OFF + (cc*TT + j2)*64 + b2];
        ep[u] = C0 - 0.5f*q + 207.f*ws[VLOG_OFF + cc] + 12.f*ws[ULOG_OFF + cc]
                + logf(wgt[b2*NC + cc]);
    }
    __syncthreads();
    if (t < 64) {
        float mx = -1e30f;
        for (int cc = 0; cc < NC; ++cc) mx = fmaxf(mx, ep[t*NC + cc]);
        float s = 0.f;
        for (int cc = 0; cc < NC; ++cc) s += expf(ep[t*NC + cc] - mx);
        nl[t] = -(mx + logf(s));
    }
    __syncthreads();
    if (t < 64) {
        float v = nl[t];
        for (int o = 32; o; o >>= 1) v += __shfl_down(v, o, 64);
        if (t == 0) {
            float sm = 0.f, sa = 0.f;
            for (int q2 = 0; q2 < 64; ++q2) {
                sm += ws[MAEC_OFF + q2];
                sa += ws[MAEA_OFF + q2];
            }
            float mse = (sm > 0.f) ? sa / sm : 0.f;
            out[0] = 0.1f * (v * (1.f/64.f)) + 0.9f * mse;
        }
    }
}

extern "C" void kernel_launch(void* const* d_in, const int* in_sizes, int n_in,
                              void* d_out, int out_size, void* d_ws, size_t ws_size,
                              hipStream_t stream) {
    const float* mu  = (const float*)d_in[0];
    const float* tg  = (const float*)d_in[1];
    const float* uns = (const float*)d_in[2];
    const float* wgt = (const float*)d_in[3];
    const float* sig = (const float*)d_in[4];
    // d_in[5] = R, unused by the reference loss
    const float* Ls  = (const float*)d_in[6];
    const float* Lt  = (const float*)d_in[7];
    float* out = (float*)d_out;
    float* ws  = (float*)d_ws;

    const int kd_lds = (TRI8 + 64*WST + 16*PTS + 64 + 256 + 16 + 12) * 4; // 159,248 B
    (void)hipFuncSetAttribute((const void*)kD,
                              hipFuncAttributeMaxDynamicSharedMemorySize, kd_lds);

    k1<<<195, 640, 0, stream>>>(Ls, Lt, mu, tg, uns, ws);
    kD<<<NC*TT, KDT, kd_lds, stream>>>(sig, mu, tg, wgt, ws, out);
}

// Round 7
// 441.711 us; speedup vs baseline: 1.8658x; 1.1575x over previous
//
#include <hip/hip_runtime.h>
#include <math.h>

#define BB 64
#define NN 207
#define TT 12
#define NC 10
#define NP 208              // padded matrix dim (pad row 207: identity)
#define TRI8 21736          // 208*209/2 packed lower triangle
#define WR 32               // RHS rows per block (64 batches / 2 blocks per (c,j))
#define WST 209             // W row stride (odd -> full bank spread)
#define PTS 244             // Pt row stride (mult of 4 for b128 alignment; rows to NP+WR=240)
#define KDT 512             // kD block size (96-VGPR sweet spot per R6)
#define NBLK 240            // kD grid: 120 (c,j) x 2 RHS halves; all co-resident (1/CU)

// ws layout (float offsets).
#define KS_OFF   0          // [C][N][N]       428490
#define DT_OFF   428490     // [C][T]          120
#define UT_OFF   428610     // [C][T][T]       1440
#define ULOG_OFF 430050     // [C]             10
#define VLOG_OFF 430060     // [C]             10
#define CNT_OFF  430070     // int completion counter (zeroed by k1)
#define MAEC_OFF 430071     // [64] mask-count slots
#define MAEA_OFF 430135     // [64] abs-sum slots
#define SSQ_OFF  430199     // [C][T][B]       7680

__device__ __forceinline__ void WB() {
    __builtin_amdgcn_wave_barrier();
    __asm__ volatile("" ::: "memory");
}

// round-robin tournament pairing: 12 players, 11 rounds, 6 disjoint pairs/round
__device__ inline void jpair(int r, int pi, int& p, int& q) {
    if (pi == 0) { p = 11; q = r % 11; }
    else { p = (r + pi) % 11; q = (r + 11 - pi) % 11; }
}

// k1 (640 thr): blocks 0..129 tiled Ks = Ls*Ls^T; block 130 = 10 wave-parallel
// barrier-free 12x12 Jacobi eigh (5 sweeps) + logdets + counter zero;
// blocks 131..194 = slot-based masked-MAE partials.
__global__ __launch_bounds__(640) void k1(const float* __restrict__ Ls,
                                          const float* __restrict__ Lt,
                                          const float* __restrict__ mu,
                                          const float* __restrict__ tg,
                                          const float* __restrict__ uns,
                                          float* __restrict__ ws) {
    __shared__ float sh[3520];
    int t = threadIdx.x;
    int blk = blockIdx.x;
    if (blk < 130) {
        int c = blk / 13, it = blk % 13, i0 = it * 16;
        float* At = sh;   // [207][16] stride 17
        for (int u = t; u < 16*NN; u += 640) {
            int k = u % NN, ii = u / NN;
            int r = i0 + ii;
            At[k*17 + ii] = (r < NN) ? Ls[(size_t)(c*NN + r)*NN + k] : 0.f;
        }
        __syncthreads();
        int j = t;
        if (j < NN) {
            float acc[16];
            #pragma unroll
            for (int ii = 0; ii < 16; ++ii) acc[ii] = 0.f;
            const float* lsr = Ls + (size_t)(c*NN + j)*NN;
            int kb = i0 + 15; if (j < kb) kb = j;   // tril
            for (int k = 0; k <= kb; ++k) {
                float g = lsr[k];
                const float* ar = At + k*17;
                #pragma unroll
                for (int ii = 0; ii < 16; ++ii) acc[ii] += g * ar[ii];
            }
            float* ksb = ws + KS_OFF + (size_t)c*NN*NN;
            #pragma unroll
            for (int ii = 0; ii < 16; ++ii) {
                int r = i0 + ii;
                if (r < NN) ksb[(size_t)r*NN + j] = acc[ii];
            }
        }
    } else if (blk == 130) {
        int wv = t >> 6, l = t & 63;      // wave wv owns component wv
        float* A  = sh + wv*304;
        float* V  = A + 144;
        float* rc = A + 288;
        float* rs = A + 294;
        for (int u = l; u < 144; u += 64) {
            int i = u / 12, j = u % 12;
            int kmax = (i < j) ? i : j;
            const float* a = Lt + wv*144 + i*12;
            const float* b = Lt + wv*144 + j*12;
            float s = 0.f;
            for (int k = 0; k <= kmax; ++k) s += a[k]*b[k];
            A[u] = s; V[u] = (i == j) ? 1.f : 0.f;
        }
        WB();
        for (int sweep = 0; sweep < 5; ++sweep)
        for (int r = 0; r < 11; ++r) {
            if (l < 6) {
                int p, q; jpair(r, l, p, q);
                float app = A[p*13], aqq = A[q*13], apq = A[p*12 + q];
                float cs = 1.f, sn = 0.f;
                if (fabsf(apq) > 1e-30f) {
                    float tau = (aqq - app) / (2.f * apq);
                    float t2 = ((tau >= 0.f) ? 1.f : -1.f) / (fabsf(tau) + sqrtf(1.f + tau*tau));
                    cs = 1.f / sqrtf(1.f + t2*t2);
                    sn = t2 * cs;
                }
                rc[l] = cs; rs[l] = sn;
            }
            WB();
            for (int u = l; u < 72; u += 64) {        // rows p,q
                int pi = u / 12, k = u % 12, p, q;
                jpair(r, pi, p, q);
                float cs = rc[pi], sn = rs[pi];
                float x = A[p*12 + k], y = A[q*12 + k];
                A[p*12 + k] = cs*x - sn*y;
                A[q*12 + k] = sn*x + cs*y;
            }
            WB();
            for (int u = l; u < 144; u += 64) {       // cols + V
                int isV = (u >= 72);
                int v2 = isV ? u - 72 : u;
                int pi = v2 / 12, i = v2 % 12, p, q;
                jpair(r, pi, p, q);
                float cs = rc[pi], sn = rs[pi];
                float* M = isV ? V : A;
                float x = M[i*12 + p], y = M[i*12 + q];
                M[i*12 + p] = cs*x - sn*y;
                M[i*12 + q] = sn*x + cs*y;
            }
            WB();
        }
        if (l < 12) ws[DT_OFF + wv*12 + l] = A[l*13];
        for (int u = l; u < 144; u += 64) ws[UT_OFF + wv*144 + u] = V[u];
        float su = 0.f;
        for (int i = l; i < NN; i += 64) su += logf(Ls[(size_t)(wv*NN + i)*NN + i]);
        for (int o = 32; o; o >>= 1) su += __shfl_down(su, o, 64);
        if (l == 0) ws[ULOG_OFF + wv] = su;
        float sv = (l < 12) ? logf(Lt[wv*144 + l*13]) : 0.f;
        for (int o = 32; o; o >>= 1) sv += __shfl_down(sv, o, 64);
        if (l == 0) ws[VLOG_OFF + wv] = sv;
        if (t == 0) *((int*)(ws + CNT_OFF)) = 0;
    } else {
        int mb = blk - 131;               // 64 MAE blocks, 2484 elems each
        int base = mb * 2484;
        float mk = 0.f, dd = 0.f;
        for (int u = base + t; u < base + 2484; u += 640) {
            float m2 = (uns[u] != 0.f) ? 1.f : 0.f;
            mk += m2;
            dd += fabsf(mu[u] - tg[u]) * m2;
        }
        for (int o = 32; o; o >>= 1) {
            mk += __shfl_down(mk, o, 64);
            dd += __shfl_down(dd, o, 64);
        }
        int wv = t >> 6, l = t & 63;
        if (l == 0) { sh[wv] = mk; sh[16 + wv] = dd; }
        __syncthreads();
        if (t == 0) {
            float a = 0.f, b2 = 0.f;
            for (int q = 0; q < 10; ++q) { a += sh[q]; b2 += sh[16 + q]; }
            ws[MAEC_OFF + mb] = a;
            ws[MAEA_OFF + mb] = b2;
        }
    }
}

// kD: blocked (P=16) Cholesky of A = Dt[c,j]*Ks_c + sig^2 I fused with forward
// substitution for a 32-RHS half (trapezoid rows) + float4 Y-transform +
// last-block logsumexp epilogue. 240 blocks (2 per (c,j)), 512 threads.
__global__ __launch_bounds__(KDT)
__attribute__((amdgpu_waves_per_eu(2, 2)))
void kD(const float* __restrict__ sig,
        const float* __restrict__ mu,
        const float* __restrict__ tg,
        const float* __restrict__ wgt,
        float* __restrict__ ws,
        float* __restrict__ out) {
    extern __shared__ float lds[];
    float* Apk = lds;                    // 21736
    float* W   = Apk + TRI8;             // 32*209 = 6688
    float* Pt  = W + WR*WST;             // 16*244 = 3904
    float* ldg = Pt + 16*PTS;            // 256 (diag block L, row-major)
    float* dnv = ldg + 256;              // 16
    float* utl = dnv + 16;               // 12
    __shared__ int lflag;
    int t = threadIdx.x;
    int bid = blockIdx.x;
    int cj = bid >> 1, hf = bid & 1;     // (c,j) index + RHS half
    int c = cj / TT, jj = cj % TT;
    float dt = ws[DT_OFF + cj];
    float sg = sig[c], sg2 = sg*sg;
    const float* KsC = ws + KS_OFF + (size_t)c*NN*NN;

    if (t < 12) utl[t] = ws[UT_OFF + c*144 + t*12 + jj];
    for (int f = t; f < TRI8; f += KDT) {
        int i = (int)((sqrtf(8.f*(float)f + 1.f) - 1.f)*0.5f);
        while ((i+1)*(i+2)/2 <= f) ++i;
        while (i*(i+1)/2 > f) --i;
        int j2 = f - i*(i+1)/2;
        float v;
        if (i == NN) v = (j2 == NN) ? 1.f : 0.f;
        else { v = dt * KsC[i*NN + j2]; if (i == j2) v += sg2; }
        Apk[f] = v;
    }
    __syncthreads();
    // Y-transform (float4 loads): W[wb][i] = sum_q (tg-mu)[b,i,q]*Ut[c][q][jj]
    for (int u = t; u < WR*NN; u += KDT) {
        int wb = u / NN, i = u - wb*NN;
        int b = hf*WR + wb;
        const float4* mp = (const float4*)(mu + (size_t)(b*NN + i)*TT);
        const float4* tp = (const float4*)(tg + (size_t)(b*NN + i)*TT);
        float4 m0 = mp[0], m1 = mp[1], m2 = mp[2];
        float4 t0 = tp[0], t1 = tp[1], t2 = tp[2];
        float s = (t0.x-m0.x)*utl[0] + (t0.y-m0.y)*utl[1] + (t0.z-m0.z)*utl[2]
                + (t0.w-m0.w)*utl[3] + (t1.x-m1.x)*utl[4] + (t1.y-m1.y)*utl[5]
                + (t1.z-m1.z)*utl[6] + (t1.w-m1.w)*utl[7] + (t2.x-m2.x)*utl[8]
                + (t2.y-m2.y)*utl[9] + (t2.z-m2.z)*utl[10] + (t2.w-m2.w)*utl[11];
        W[wb*WST + i] = s;
    }
    if (t < WR) W[t*WST + NN] = 0.f;
    __syncthreads();

    for (int p = 0; p < 13; ++p) {
        int k0 = p*16, k1 = k0 + 16;
        int nA = NP - k1;
        int nsolve = nA + WR;            // always a multiple of 16
        // ---- preload row-solve operands (independent of the diag factor;
        //      overlaps their LDS latency with wave0's serial diag phase)
        bool act = (t < nsolve);
        bool isW = act && (t >= nA);
        float arow[16];
        int abase = 0, wb = 0;
        if (act) {
            if (!isW) {
                int r = k1 + t;
                abase = ((r*(r+1)) >> 1) + k0;
                #pragma unroll
                for (int m = 0; m < 16; ++m) arow[m] = Apk[abase + m];
            } else {
                wb = t - nA;
                #pragma unroll
                for (int m = 0; m < 16; ++m) arow[m] = W[wb*WST + k0 + m];
            }
        }
        // ---- 16x16 diag factor, wave 0, registers + shuffles
        if (t < 64) {
            int r = t;
            int rr = (r < 16) ? (k0 + r) : k0;
            int base = ((rr*(rr+1)) >> 1) + k0;
            float a[16];
            #pragma unroll
            for (int m = 0; m < 16; ++m) a[m] = Apk[base + m];
            #pragma unroll
            for (int kk = 0; kk < 16; ++kk) {
                float d = __shfl(a[kk], kk);
                float dv = 1.0f / sqrtf(d);
                if (t == 0) dnv[kk] = dv;
                if (r < 16 && r > kk) a[kk] *= dv;
                #pragma unroll
                for (int j2 = kk+1; j2 < 16; ++j2) {
                    float v = __shfl(a[kk], j2);
                    if (r < 16 && r > kk && j2 <= r) a[j2] -= a[kk]*v;
                }
            }
            if (r < 16) {
                #pragma unroll
                for (int m = 0; m < 16; ++m) ldg[r*16 + m] = a[m];
            }
        }
        __syncthreads();
        // ---- unified panel row solve (uses preloaded arow)
        if (act) {
            #pragma unroll
            for (int kk = 0; kk < 16; ++kk) {
                float x = arow[kk];
                #pragma unroll
                for (int m = 0; m < kk; ++m) x -= arow[m] * ldg[kk*16 + m];
                arow[kk] = x * dnv[kk];
            }
            int rho = isW ? (NP + wb) : (k1 + t);
            if (!isW) {
                #pragma unroll
                for (int m = 0; m < 16; ++m) Apk[abase + m] = arow[m];
            } else {
                #pragma unroll
                for (int m = 0; m < 16; ++m) W[wb*WST + k0 + m] = arow[m];
            }
            #pragma unroll
            for (int m = 0; m < 16; ++m) Pt[m*PTS + rho] = arow[m];
        }
        __syncthreads();
        // ---- trailing rank-16 update, 64x128 thread tile, 4x4 microtiles
        int nc2 = NP - k1;
        int nr2 = nc2 + WR;
        if (nc2 > 0) {
            int ty = t >> 5, tx = t & 31;     // 16 x 32 threads
            for (int rg = 0; rg < nr2; rg += 64) {
                int rbase = k1 + rg + 4*ty;
                if (rbase >= NP + WR) continue;
                for (int cg = 0; cg < nc2; cg += 128) {
                    int cbase = k1 + cg + 4*tx;
                    if (cbase >= NP) continue;
                    if (rbase + 3 < cbase && rbase + 3 < NP) continue;
                    float acc[4][4];
                    #pragma unroll
                    for (int a2 = 0; a2 < 4; ++a2)
                        #pragma unroll
                        for (int b2 = 0; b2 < 4; ++b2) acc[a2][b2] = 0.f;
                    #pragma unroll
                    for (int kk = 0; kk < 16; ++kk) {
                        float4 av = *(const float4*)(Pt + kk*PTS + rbase);
                        float4 bv = *(const float4*)(Pt + kk*PTS + cbase);
                        acc[0][0] += av.x*bv.x; acc[0][1] += av.x*bv.y;
                        acc[0][2] += av.x*bv.z; acc[0][3] += av.x*bv.w;
                        acc[1][0] += av.y*bv.x; acc[1][1] += av.y*bv.y;
                        acc[1][2] += av.y*bv.z; acc[1][3] += av.y*bv.w;
                        acc[2][0] += av.z*bv.x; acc[2][1] += av.z*bv.y;
                        acc[2][2] += av.z*bv.z; acc[2][3] += av.z*bv.w;
                        acc[3][0] += av.w*bv.x; acc[3][1] += av.w*bv.y;
                        acc[3][2] += av.w*bv.z; acc[3][3] += av.w*bv.w;
                    }
                    #pragma unroll
                    for (int ri2 = 0; ri2 < 4; ++ri2) {
                        int rho = rbase + ri2;
                        if (rho >= NP + WR) continue;
                        #pragma unroll
                        for (int ci2 = 0; ci2 < 4; ++ci2) {
                            int jc = cbase + ci2;
                            if (jc >= NP) continue;
                            if (rho < NP) {
                                if (jc <= rho)
                                    Apk[((rho*(rho+1))>>1) + jc] -= acc[ri2][ci2];
                            } else {
                                W[(rho - NP)*WST + jc] -= acc[ri2][ci2];
                            }
                        }
                    }
                }
            }
        }
        __syncthreads();
    }
    // quad = ||L^-1 y||^2 per batch: 32 batches x 16 segments of 13
    {
        int b = t >> 4, seg = t & 15;
        float part = 0.f;
        int ks = seg * 13;
        for (int k = ks; k < ks + 13; ++k) { float z = W[b*WST + k]; part += z*z; }
        part += __shfl_down(part, 8, 16);
        part += __shfl_down(part, 4, 16);
        part += __shfl_down(part, 2, 16);
        part += __shfl_down(part, 1, 16);
        if (seg == 0) ws[SSQ_OFF + (cj << 6) + hf*WR + b] = part;
    }
    // last-block epilogue
    __threadfence();
    __syncthreads();
    if (t == 0) {
        int old = atomicAdd((int*)(ws + CNT_OFF), 1);
        lflag = (old == NBLK - 1) ? 1 : 0;
    }
    __syncthreads();
    if (!lflag) return;
    __threadfence();
    float* ep = Apk;            // reuse LDS: 640 ll values + 64 nll
    float* nl = Apk + 640;
    const float C0 = -0.5f * 2484.0f * 1.8378770664093453f;
    for (int u = t; u < 640; u += KDT) {
        int b2 = u / NC, cc = u % NC;
        float q = 0.f;
        for (int j2 = 0; j2 < TT; ++j2) q += ws[SSQ_OFF + (cc*TT + j2)*64 + b2];
        ep[u] = C0 - 0.5f*q + 207.f*ws[VLOG_OFF + cc] + 12.f*ws[ULOG_OFF + cc]
                + logf(wgt[b2*NC + cc]);
    }
    __syncthreads();
    if (t < 64) {
        float mx = -1e30f;
        for (int cc = 0; cc < NC; ++cc) mx = fmaxf(mx, ep[t*NC + cc]);
        float s = 0.f;
        for (int cc = 0; cc < NC; ++cc) s += expf(ep[t*NC + cc] - mx);
        nl[t] = -(mx + logf(s));
    }
    __syncthreads();
    if (t < 64) {
        float v = nl[t];
        for (int o = 32; o; o >>= 1) v += __shfl_down(v, o, 64);
        if (t == 0) {
            float sm = 0.f, sa = 0.f;
            for (int q2 = 0; q2 < 64; ++q2) {
                sm += ws[MAEC_OFF + q2];
                sa += ws[MAEA_OFF + q2];
            }
            float mse = (sm > 0.f) ? sa / sm : 0.f;
            out[0] = 0.1f * (v * (1.f/64.f)) + 0.9f * mse;
        }
    }
}

extern "C" void kernel_launch(void* const* d_in, const int* in_sizes, int n_in,
                              void* d_out, int out_size, void* d_ws, size_t ws_size,
                              hipStream_t stream) {
    const float* mu  = (const float*)d_in[0];
    const float* tg  = (const float*)d_in[1];
    const float* uns = (const float*)d_in[2];
    const float* wgt = (const float*)d_in[3];
    const float* sig = (const float*)d_in[4];
    // d_in[5] = R, unused by the reference loss
    const float* Ls  = (const float*)d_in[6];
    const float* Lt  = (const float*)d_in[7];
    float* out = (float*)d_out;
    float* ws  = (float*)d_ws;

    const int kd_lds = (TRI8 + WR*WST + 16*PTS + 256 + 16 + 12) * 4; // 130,448 B
    (void)hipFuncSetAttribute((const void*)kD,
                              hipFuncAttributeMaxDynamicSharedMemorySize, kd_lds);

    k1<<<195, 640, 0, stream>>>(Ls, Lt, mu, tg, uns, ws);
    kD<<<NBLK, KDT, kd_lds, stream>>>(sig, mu, tg, wgt, ws, out);
}

// Round 8
// 428.254 us; speedup vs baseline: 1.9245x; 1.0314x over previous
//
#include <hip/hip_runtime.h>
#include <math.h>

#define BB 64
#define NN 207
#define TT 12
#define NC 10
#define NP 208              // padded matrix dim (pad row 207: identity)
#define TRIP 22048          // 4-aligned packed lower triangle (rows padded to x4)
#define QTOT 5512           // TRIP/4 quad-chunks for staging
#define WR 32               // RHS rows per block (64 batches / 2 blocks per (c,j))
#define WST 212             // W row stride (mult of 4 for b128; 53 words, odd -> spread)
#define PTS 244             // Pt row stride (mult of 4; rows k1..207 + 32 W rows at 208..239)
#define KDT 512             // kD block size (96-VGPR no-spill regime per R6/R7)
#define NBLK 240            // kD grid: 120 (c,j) x 2 RHS halves; all co-resident (1/CU)

// ws layout (float offsets).
#define KS_OFF   0          // [C][N][N]       428490
#define DT_OFF   428490     // [C][T]          120
#define UT_OFF   428610     // [C][T][T]       1440
#define ULOG_OFF 430050     // [C]             10
#define VLOG_OFF 430060     // [C]             10
#define CNT_OFF  430070     // int completion counter (zeroed by k1)
#define MAEC_OFF 430071     // [64] mask-count slots
#define MAEA_OFF 430135     // [64] abs-sum slots
#define SSQ_OFF  430199     // [C][T][B]       7680

// 4-aligned packed-triangle row offset: roff(r) = tri(r) + padsum(r),
// padsum(r) = 6*(r/4) + {0,3,5,6}[r%4]; every row starts 16B-aligned.
__device__ __forceinline__ int roff(int r) {
    return ((r*(r+1)) >> 1) + 6*(r >> 2) + ((0x6530 >> ((r & 3) << 2)) & 15);
}

__device__ __forceinline__ void WB() {
    __builtin_amdgcn_wave_barrier();
    __asm__ volatile("" ::: "memory");
}

// round-robin tournament pairing: 12 players, 11 rounds, 6 disjoint pairs/round
__device__ inline void jpair(int r, int pi, int& p, int& q) {
    if (pi == 0) { p = 11; q = r % 11; }
    else { p = (r + pi) % 11; q = (r + 11 - pi) % 11; }
}

// k1 (640 thr): blocks 0..129 tiled Ks = Ls*Ls^T; block 130 = 10 wave-parallel
// barrier-free 12x12 Jacobi eigh (5 sweeps) + logdets + counter zero;
// blocks 131..194 = slot-based masked-MAE partials.  (unchanged from R7)
__global__ __launch_bounds__(640) void k1(const float* __restrict__ Ls,
                                          const float* __restrict__ Lt,
                                          const float* __restrict__ mu,
                                          const float* __restrict__ tg,
                                          const float* __restrict__ uns,
                                          float* __restrict__ ws) {
    __shared__ float sh[3520];
    int t = threadIdx.x;
    int blk = blockIdx.x;
    if (blk < 130) {
        int c = blk / 13, it = blk % 13, i0 = it * 16;
        float* At = sh;   // [207][16] stride 17
        for (int u = t; u < 16*NN; u += 640) {
            int k = u % NN, ii = u / NN;
            int r = i0 + ii;
            At[k*17 + ii] = (r < NN) ? Ls[(size_t)(c*NN + r)*NN + k] : 0.f;
        }
        __syncthreads();
        int j = t;
        if (j < NN) {
            float acc[16];
            #pragma unroll
            for (int ii = 0; ii < 16; ++ii) acc[ii] = 0.f;
            const float* lsr = Ls + (size_t)(c*NN + j)*NN;
            int kb = i0 + 15; if (j < kb) kb = j;   // tril
            for (int k = 0; k <= kb; ++k) {
                float g = lsr[k];
                const float* ar = At + k*17;
                #pragma unroll
                for (int ii = 0; ii < 16; ++ii) acc[ii] += g * ar[ii];
            }
            float* ksb = ws + KS_OFF + (size_t)c*NN*NN;
            #pragma unroll
            for (int ii = 0; ii < 16; ++ii) {
                int r = i0 + ii;
                if (r < NN) ksb[(size_t)r*NN + j] = acc[ii];
            }
        }
    } else if (blk == 130) {
        int wv = t >> 6, l = t & 63;      // wave wv owns component wv
        float* A  = sh + wv*304;
        float* V  = A + 144;
        float* rc = A + 288;
        float* rs = A + 294;
        for (int u = l; u < 144; u += 64) {
            int i = u / 12, j = u % 12;
            int kmax = (i < j) ? i : j;
            const float* a = Lt + wv*144 + i*12;
            const float* b = Lt + wv*144 + j*12;
            float s = 0.f;
            for (int k = 0; k <= kmax; ++k) s += a[k]*b[k];
            A[u] = s; V[u] = (i == j) ? 1.f : 0.f;
        }
        WB();
        for (int sweep = 0; sweep < 5; ++sweep)
        for (int r = 0; r < 11; ++r) {
            if (l < 6) {
                int p, q; jpair(r, l, p, q);
                float app = A[p*13], aqq = A[q*13], apq = A[p*12 + q];
                float cs = 1.f, sn = 0.f;
                if (fabsf(apq) > 1e-30f) {
                    float tau = (aqq - app) / (2.f * apq);
                    float t2 = ((tau >= 0.f) ? 1.f : -1.f) / (fabsf(tau) + sqrtf(1.f + tau*tau));
                    cs = 1.f / sqrtf(1.f + t2*t2);
                    sn = t2 * cs;
                }
                rc[l] = cs; rs[l] = sn;
            }
            WB();
            for (int u = l; u < 72; u += 64) {        // rows p,q
                int pi = u / 12, k = u % 12, p, q;
                jpair(r, pi, p, q);
                float cs = rc[pi], sn = rs[pi];
                float x = A[p*12 + k], y = A[q*12 + k];
                A[p*12 + k] = cs*x - sn*y;
                A[q*12 + k] = sn*x + cs*y;
            }
            WB();
            for (int u = l; u < 144; u += 64) {       // cols + V
                int isV = (u >= 72);
                int v2 = isV ? u - 72 : u;
                int pi = v2 / 12, i = v2 % 12, p, q;
                jpair(r, pi, p, q);
                float cs = rc[pi], sn = rs[pi];
                float* M = isV ? V : A;
                float x = M[i*12 + p], y = M[i*12 + q];
                M[i*12 + p] = cs*x - sn*y;
                M[i*12 + q] = sn*x + cs*y;
            }
            WB();
        }
        if (l < 12) ws[DT_OFF + wv*12 + l] = A[l*13];
        for (int u = l; u < 144; u += 64) ws[UT_OFF + wv*144 + u] = V[u];
        float su = 0.f;
        for (int i = l; i < NN; i += 64) su += logf(Ls[(size_t)(wv*NN + i)*NN + i]);
        for (int o = 32; o; o >>= 1) su += __shfl_down(su, o, 64);
        if (l == 0) ws[ULOG_OFF + wv] = su;
        float sv = (l < 12) ? logf(Lt[wv*144 + l*13]) : 0.f;
        for (int o = 32; o; o >>= 1) sv += __shfl_down(sv, o, 64);
        if (l == 0) ws[VLOG_OFF + wv] = sv;
        if (t == 0) *((int*)(ws + CNT_OFF)) = 0;
    } else {
        int mb = blk - 131;               // 64 MAE blocks, 2484 elems each
        int base = mb * 2484;
        float mk = 0.f, dd = 0.f;
        for (int u = base + t; u < base + 2484; u += 640) {
            float m2 = (uns[u] != 0.f) ? 1.f : 0.f;
            mk += m2;
            dd += fabsf(mu[u] - tg[u]) * m2;
        }
        for (int o = 32; o; o >>= 1) {
            mk += __shfl_down(mk, o, 64);
            dd += __shfl_down(dd, o, 64);
        }
        int wv = t >> 6, l = t & 63;
        if (l == 0) { sh[wv] = mk; sh[16 + wv] = dd; }
        __syncthreads();
        if (t == 0) {
            float a = 0.f, b2 = 0.f;
            for (int q = 0; q < 10; ++q) { a += sh[q]; b2 += sh[16 + q]; }
            ws[MAEC_OFF + mb] = a;
            ws[MAEA_OFF + mb] = b2;
        }
    }
}

// kD: blocked (P=16) Cholesky of A = Dt[c,j]*Ks_c + sig^2 I fused with forward
// substitution for a 32-RHS half. R8 changes: 4-aligned triangle -> b128 RMW
// SYRK writeback (was the bank-conflict source); 8x4 microtiles on 128x128
// tiles (fewer LDS reads/MAC); dead stores dropped (L-panel + solved-z);
// fixed W thread slots t in [192,224) -> register ssq accumulation.
__global__ __launch_bounds__(KDT)
__attribute__((amdgpu_waves_per_eu(2, 2)))
void kD(const float* __restrict__ sig,
        const float* __restrict__ mu,
        const float* __restrict__ tg,
        const float* __restrict__ wgt,
        float* __restrict__ ws,
        float* __restrict__ out) {
    extern __shared__ float lds[];
    float* Apk = lds;                    // TRIP = 22048
    float* W   = Apk + TRIP;             // 32*212 = 6784
    float* Pt  = W + WR*WST;             // 16*244 = 3904
    float* ldg = Pt + 16*PTS;            // 256 (diag block L, row-major)
    float* dnv = ldg + 256;              // 16
    float* utl = dnv + 16;               // 12
    __shared__ int lflag;
    int t = threadIdx.x;
    int bid = blockIdx.x;
    int cj = bid >> 1, hf = bid & 1;     // (c,j) index + RHS half
    int c = cj / TT, jj = cj % TT;
    float dt = ws[DT_OFF + cj];
    float sg = sig[c], sg2 = sg*sg;
    const float* KsC = ws + KS_OFF + (size_t)c*NN*NN;

    if (t < 12) utl[t] = ws[UT_OFF + c*144 + t*12 + jj];
    // stage padded-aligned triangle, one float4 chunk per iteration
    for (int f = t; f < QTOT; f += KDT) {
        int r = (int)((sqrtf(32.f*(float)f + 25.f) - 5.f)*0.5f);
        while ((roff(r+1) >> 2) <= f) ++r;
        while ((roff(r) >> 2) > f) --r;
        int c4 = (f - (roff(r) >> 2)) << 2;
        float4 v;
        float* ve = (float*)&v;
        #pragma unroll
        for (int e = 0; e < 4; ++e) {
            int cc = c4 + e;
            float x;
            if (r == NN) x = (cc == NN) ? 1.f : 0.f;
            else if (cc > r) x = 0.f;
            else { x = dt * KsC[r*NN + cc]; if (cc == r) x += sg2; }
            ve[e] = x;
        }
        *(float4*)(Apk + roff(r) + c4) = v;
    }
    __syncthreads();
    // Y-transform (float4 loads): W[wb][i] = sum_q (tg-mu)[b,i,q]*Ut[c][q][jj]
    for (int u = t; u < WR*NN; u += KDT) {
        int wb = u / NN, i = u - wb*NN;
        int b = hf*WR + wb;
        const float4* mp = (const float4*)(mu + (size_t)(b*NN + i)*TT);
        const float4* tp = (const float4*)(tg + (size_t)(b*NN + i)*TT);
        float4 m0 = mp[0], m1 = mp[1], m2 = mp[2];
        float4 t0 = tp[0], t1 = tp[1], t2 = tp[2];
        float s = (t0.x-m0.x)*utl[0] + (t0.y-m0.y)*utl[1] + (t0.z-m0.z)*utl[2]
                + (t0.w-m0.w)*utl[3] + (t1.x-m1.x)*utl[4] + (t1.y-m1.y)*utl[5]
                + (t1.z-m1.z)*utl[6] + (t1.w-m1.w)*utl[7] + (t2.x-m2.x)*utl[8]
                + (t2.y-m2.y)*utl[9] + (t2.z-m2.z)*utl[10] + (t2.w-m2.w)*utl[11];
        W[wb*WST + i] = s;
    }
    if (t < WR) W[t*WST + NN] = 0.f;
    __syncthreads();

    float zacc = 0.f;                    // per-W-thread ssq accumulator
    for (int p = 0; p < 13; ++p) {
        int k0 = p*16, k1 = k0 + 16;
        int nA = NP - k1;                // <= 192
        // solve-thread roles: A rows t in [0,nA); W rows t in [192,224) (fixed)
        bool isW = (t >= 192 && t < 224);
        bool isA = (t < nA);
        float arow[16];
        int wb = t - 192;
        // ---- preload row-solve operands (b128; overlaps wave0's diag phase)
        if (isA) {
            int abase = roff(k1 + t) + k0;
            float4 a0 = *(const float4*)(Apk + abase);
            float4 a1 = *(const float4*)(Apk + abase + 4);
            float4 a2 = *(const float4*)(Apk + abase + 8);
            float4 a3 = *(const float4*)(Apk + abase + 12);
            arow[0]=a0.x; arow[1]=a0.y; arow[2]=a0.z; arow[3]=a0.w;
            arow[4]=a1.x; arow[5]=a1.y; arow[6]=a1.z; arow[7]=a1.w;
            arow[8]=a2.x; arow[9]=a2.y; arow[10]=a2.z; arow[11]=a2.w;
            arow[12]=a3.x; arow[13]=a3.y; arow[14]=a3.z; arow[15]=a3.w;
        } else if (isW) {
            int wbase = wb*WST + k0;
            float4 a0 = *(const float4*)(W + wbase);
            float4 a1 = *(const float4*)(W + wbase + 4);
            float4 a2 = *(const float4*)(W + wbase + 8);
            float4 a3 = *(const float4*)(W + wbase + 12);
            arow[0]=a0.x; arow[1]=a0.y; arow[2]=a0.z; arow[3]=a0.w;
            arow[4]=a1.x; arow[5]=a1.y; arow[6]=a1.z; arow[7]=a1.w;
            arow[8]=a2.x; arow[9]=a2.y; arow[10]=a2.z; arow[11]=a2.w;
            arow[12]=a3.x; arow[13]=a3.y; arow[14]=a3.z; arow[15]=a3.w;
        }
        // ---- 16x16 diag factor, wave 0, registers + shuffles
        if (t < 64) {
            int r = t;
            int rr = (r < 16) ? (k0 + r) : k0;
            int base = roff(rr) + k0;
            float a[16];
            #pragma unroll
            for (int m = 0; m < 16; ++m) a[m] = Apk[base + m];
            #pragma unroll
            for (int kk = 0; kk < 16; ++kk) {
                float d = __shfl(a[kk], kk);
                float dv = 1.0f / sqrtf(d);
                if (t == 0) dnv[kk] = dv;
                if (r < 16 && r > kk) a[kk] *= dv;
                #pragma unroll
                for (int j2 = kk+1; j2 < 16; ++j2) {
                    float v = __shfl(a[kk], j2);
                    if (r < 16 && r > kk && j2 <= r) a[j2] -= a[kk]*v;
                }
            }
            if (r < 16) {
                #pragma unroll
                for (int m = 0; m < 16; ++m) ldg[r*16 + m] = a[m];
            }
        }
        __syncthreads();
        // ---- unified panel row solve -> Pt only (L-panel/z stores are dead)
        if (isA || isW) {
            #pragma unroll
            for (int kk = 0; kk < 16; ++kk) {
                float x = arow[kk];
                #pragma unroll
                for (int m = 0; m < kk; ++m) x -= arow[m] * ldg[kk*16 + m];
                arow[kk] = x * dnv[kk];
            }
            int rho = isW ? (NP + wb) : (k1 + t);
            if (isW) {
                #pragma unroll
                for (int m = 0; m < 16; ++m) zacc += arow[m]*arow[m];
            }
            #pragma unroll
            for (int m = 0; m < 16; ++m) Pt[m*PTS + rho] = arow[m];
        }
        __syncthreads();
        // ---- trailing rank-16 update, 128x128 tiles, 8x4 microtiles
        int nc2 = NP - k1;
        int nr2 = nc2 + WR;
        if (nc2 > 0) {
            int ty = t >> 5, tx = t & 31;     // 16 x 32 threads
            for (int rg = 0; rg < nr2; rg += 128) {
                int rbase = k1 + rg + 8*ty;
                if (rbase >= NP + WR) continue;
                for (int cg = 0; cg < nc2; cg += 128) {
                    int cbase = k1 + cg + 4*tx;
                    if (cbase >= NP) continue;
                    if (rbase + 7 < cbase && rbase + 7 < NP) continue;
                    float4 acc[8];
                    #pragma unroll
                    for (int a2 = 0; a2 < 8; ++a2) acc[a2] = make_float4(0.f,0.f,0.f,0.f);
                    #pragma unroll
                    for (int kk = 0; kk < 16; ++kk) {
                        const float* pr = Pt + kk*PTS;
                        float4 a0 = *(const float4*)(pr + rbase);
                        float4 a1 = *(const float4*)(pr + rbase + 4);
                        float4 bv = *(const float4*)(pr + cbase);
                        float av[8] = {a0.x,a0.y,a0.z,a0.w,a1.x,a1.y,a1.z,a1.w};
                        #pragma unroll
                        for (int ri = 0; ri < 8; ++ri) {
                            acc[ri].x += av[ri]*bv.x;
                            acc[ri].y += av[ri]*bv.y;
                            acc[ri].z += av[ri]*bv.z;
                            acc[ri].w += av[ri]*bv.w;
                        }
                    }
                    int ro = roff(rbase);
                    #pragma unroll
                    for (int ri = 0; ri < 8; ++ri) {
                        int rho = rbase + ri;
                        if (rho >= NP) {                    // W row: full f4 RMW
                            float* wp = W + (rho - NP)*WST + cbase;
                            float4 w = *(float4*)wp;
                            w.x -= acc[ri].x; w.y -= acc[ri].y;
                            w.z -= acc[ri].z; w.w -= acc[ri].w;
                            *(float4*)wp = w;
                        } else if (cbase + 3 <= rho) {      // full f4 RMW in triangle
                            float* ap = Apk + ro + cbase;
                            float4 w = *(float4*)ap;
                            w.x -= acc[ri].x; w.y -= acc[ri].y;
                            w.z -= acc[ri].z; w.w -= acc[ri].w;
                            *(float4*)ap = w;
                        } else if (cbase <= rho) {          // diagonal straddle
                            float* ap = Apk + ro;
                            const float* af = (const float*)&acc[ri];
                            #pragma unroll
                            for (int e = 0; e < 4; ++e) {
                                int jc = cbase + e;
                                if (jc <= rho) ap[jc] -= af[e];
                            }
                        }
                        ro += (rho + 4) & ~3;               // roff(rho+1)
                    }
                }
            }
        }
        __syncthreads();
    }
    // ssq: W threads hold their batch's full ||z||^2 in zacc
    if (t >= 192 && t < 224)
        ws[SSQ_OFF + (cj << 6) + hf*WR + (t - 192)] = zacc;
    // last-block epilogue
    __threadfence();
    __syncthreads();
    if (t == 0) {
        int old = atomicAdd((int*)(ws + CNT_OFF), 1);
        lflag = (old == NBLK - 1) ? 1 : 0;
    }
    __syncthreads();
    if (!lflag) return;
    __threadfence();
    float* ep = Apk;            // reuse LDS: 640 ll values + 64 nll
    float* nl = Apk + 640;
    const float C0 = -0.5f * 2484.0f * 1.8378770664093453f;
    for (int u = t; u < 640; u += KDT) {
        int b2 = u / NC, cc = u % NC;
        float q = 0.f;
        for (int j2 = 0; j2 < TT; ++j2) q += ws[SSQ_OFF + (cc*TT + j2)*64 + b2];
        ep[u] = C0 - 0.5f*q + 207.f*ws[VLOG_OFF + cc] + 12.f*ws[ULOG_OFF + cc]
                + logf(wgt[b2*NC + cc]);
    }
    __syncthreads();
    if (t < 64) {
        float mx = -1e30f;
        for (int cc = 0; cc < NC; ++cc) mx = fmaxf(mx, ep[t*NC + cc]);
        float s = 0.f;
        for (int cc = 0; cc < NC; ++cc) s += expf(ep[t*NC + cc] - mx);
        nl[t] = -(mx + logf(s));
    }
    __syncthreads();
    if (t < 64) {
        float v = nl[t];
        for (int o = 32; o; o >>= 1) v += __shfl_down(v, o, 64);
        if (t == 0) {
            float sm = 0.f, sa = 0.f;
            for (int q2 = 0; q2 < 64; ++q2) {
                sm += ws[MAEC_OFF + q2];
                sa += ws[MAEA_OFF + q2];
            }
            float mse = (sm > 0.f) ? sa / sm : 0.f;
            out[0] = 0.1f * (v * (1.f/64.f)) + 0.9f * mse;
        }
    }
}

extern "C" void kernel_launch(void* const* d_in, const int* in_sizes, int n_in,
                              void* d_out, int out_size, void* d_ws, size_t ws_size,
                              hipStream_t stream) {
    const float* mu  = (const float*)d_in[0];
    const float* tg  = (const float*)d_in[1];
    const float* uns = (const float*)d_in[2];
    const float* wgt = (const float*)d_in[3];
    const float* sig = (const float*)d_in[4];
    // d_in[5] = R, unused by the reference loss
    const float* Ls  = (const float*)d_in[6];
    const float* Lt  = (const float*)d_in[7];
    float* out = (float*)d_out;
    float* ws  = (float*)d_ws;

    const int kd_lds = (TRIP + WR*WST + 16*PTS + 256 + 16 + 12) * 4; // 132,080 B
    (void)hipFuncSetAttribute((const void*)kD,
                              hipFuncAttributeMaxDynamicSharedMemorySize, kd_lds);

    k1<<<195, 640, 0, stream>>>(Ls, Lt, mu, tg, uns, ws);
    kD<<<NBLK, KDT, kd_lds, stream>>>(sig, mu, tg, wgt, ws, out);
}

// Round 9
// 421.760 us; speedup vs baseline: 1.9541x; 1.0154x over previous
//
#include <hip/hip_runtime.h>
#include <math.h>

#define BB 64
#define NN 207
#define TT 12
#define NC 10
#define NP 208              // padded matrix dim (pad row 207: identity)
#define TRIP 22048          // 4-aligned packed lower triangle (rows padded to x4)
#define QTOT 5512           // TRIP/4 quad-chunks for staging
#define WR 32               // RHS rows per block (64 batches / 2 blocks per (c,j))
#define WST 212             // W row stride (mult of 4 for b128; 53 banks-spread)
#define PTS 244             // Pt row stride (mult of 4; rows k1..207 + 32 W rows at 208..239)
#define KDT 512             // kD block size (96-VGPR no-spill regime per R6/R7)
#define NBLK 240            // kD grid: 120 (c,j) x 2 RHS halves; all co-resident (1/CU)

// ws layout (float offsets).
#define KS_OFF   0          // [C][N][N]       428490
#define DT_OFF   428490     // [C][T]          120
#define UT_OFF   428610     // [C][T][T]       1440
#define ULOG_OFF 430050     // [C]             10
#define VLOG_OFF 430060     // [C]             10
#define CNT_OFF  430070     // int completion counter (zeroed by k1)
#define MAEC_OFF 430071     // [64] mask-count slots
#define MAEA_OFF 430135     // [64] abs-sum slots
#define SSQ_OFF  430199     // [C][T][B]       7680

// 4-aligned packed-triangle row offset: roff(r) = tri(r) + padsum(r),
// padsum(r) = 6*(r/4) + {0,3,5,6}[r%4]; every row starts 16B-aligned.
__device__ __forceinline__ int roff(int r) {
    return ((r*(r+1)) >> 1) + 6*(r >> 2) + ((0x6530 >> ((r & 3) << 2)) & 15);
}

__device__ __forceinline__ void WB() {
    __builtin_amdgcn_wave_barrier();
    __asm__ volatile("" ::: "memory");
}

// round-robin tournament pairing: 12 players, 11 rounds, 6 disjoint pairs/round
__device__ inline void jpair(int r, int pi, int& p, int& q) {
    if (pi == 0) { p = 11; q = r % 11; }
    else { p = (r + pi) % 11; q = (r + 11 - pi) % 11; }
}

// k1 (640 thr): blocks 0..129 tiled Ks = Ls*Ls^T; block 130 = 10 wave-parallel
// barrier-free 12x12 Jacobi eigh (5 sweeps) + logdets + counter zero;
// blocks 131..194 = slot-based masked-MAE partials.  (unchanged)
__global__ __launch_bounds__(640) void k1(const float* __restrict__ Ls,
                                          const float* __restrict__ Lt,
                                          const float* __restrict__ mu,
                                          const float* __restrict__ tg,
                                          const float* __restrict__ uns,
                                          float* __restrict__ ws) {
    __shared__ float sh[3520];
    int t = threadIdx.x;
    int blk = blockIdx.x;
    if (blk < 130) {
        int c = blk / 13, it = blk % 13, i0 = it * 16;
        float* At = sh;   // [207][16] stride 17
        for (int u = t; u < 16*NN; u += 640) {
            int k = u % NN, ii = u / NN;
            int r = i0 + ii;
            At[k*17 + ii] = (r < NN) ? Ls[(size_t)(c*NN + r)*NN + k] : 0.f;
        }
        __syncthreads();
        int j = t;
        if (j < NN) {
            float acc[16];
            #pragma unroll
            for (int ii = 0; ii < 16; ++ii) acc[ii] = 0.f;
            const float* lsr = Ls + (size_t)(c*NN + j)*NN;
            int kb = i0 + 15; if (j < kb) kb = j;   // tril
            for (int k = 0; k <= kb; ++k) {
                float g = lsr[k];
                const float* ar = At + k*17;
                #pragma unroll
                for (int ii = 0; ii < 16; ++ii) acc[ii] += g * ar[ii];
            }
            float* ksb = ws + KS_OFF + (size_t)c*NN*NN;
            #pragma unroll
            for (int ii = 0; ii < 16; ++ii) {
                int r = i0 + ii;
                if (r < NN) ksb[(size_t)r*NN + j] = acc[ii];
            }
        }
    } else if (blk == 130) {
        int wv = t >> 6, l = t & 63;      // wave wv owns component wv
        float* A  = sh + wv*304;
        float* V  = A + 144;
        float* rc = A + 288;
        float* rs = A + 294;
        for (int u = l; u < 144; u += 64) {
            int i = u / 12, j = u % 12;
            int kmax = (i < j) ? i : j;
            const float* a = Lt + wv*144 + i*12;
            const float* b = Lt + wv*144 + j*12;
            float s = 0.f;
            for (int k = 0; k <= kmax; ++k) s += a[k]*b[k];
            A[u] = s; V[u] = (i == j) ? 1.f : 0.f;
        }
        WB();
        for (int sweep = 0; sweep < 5; ++sweep)
        for (int r = 0; r < 11; ++r) {
            if (l < 6) {
                int p, q; jpair(r, l, p, q);
                float app = A[p*13], aqq = A[q*13], apq = A[p*12 + q];
                float cs = 1.f, sn = 0.f;
                if (fabsf(apq) > 1e-30f) {
                    float tau = (aqq - app) / (2.f * apq);
                    float t2 = ((tau >= 0.f) ? 1.f : -1.f) / (fabsf(tau) + sqrtf(1.f + tau*tau));
                    cs = 1.f / sqrtf(1.f + t2*t2);
                    sn = t2 * cs;
                }
                rc[l] = cs; rs[l] = sn;
            }
            WB();
            for (int u = l; u < 72; u += 64) {        // rows p,q
                int pi = u / 12, k = u % 12, p, q;
                jpair(r, pi, p, q);
                float cs = rc[pi], sn = rs[pi];
                float x = A[p*12 + k], y = A[q*12 + k];
                A[p*12 + k] = cs*x - sn*y;
                A[q*12 + k] = sn*x + cs*y;
            }
            WB();
            for (int u = l; u < 144; u += 64) {       // cols + V
                int isV = (u >= 72);
                int v2 = isV ? u - 72 : u;
                int pi = v2 / 12, i = v2 % 12, p, q;
                jpair(r, pi, p, q);
                float cs = rc[pi], sn = rs[pi];
                float* M = isV ? V : A;
                float x = M[i*12 + p], y = M[i*12 + q];
                M[i*12 + p] = cs*x - sn*y;
                M[i*12 + q] = sn*x + cs*y;
            }
            WB();
        }
        if (l < 12) ws[DT_OFF + wv*12 + l] = A[l*13];
        for (int u = l; u < 144; u += 64) ws[UT_OFF + wv*144 + u] = V[u];
        float su = 0.f;
        for (int i = l; i < NN; i += 64) su += logf(Ls[(size_t)(wv*NN + i)*NN + i]);
        for (int o = 32; o; o >>= 1) su += __shfl_down(su, o, 64);
        if (l == 0) ws[ULOG_OFF + wv] = su;
        float sv = (l < 12) ? logf(Lt[wv*144 + l*13]) : 0.f;
        for (int o = 32; o; o >>= 1) sv += __shfl_down(sv, o, 64);
        if (l == 0) ws[VLOG_OFF + wv] = sv;
        if (t == 0) *((int*)(ws + CNT_OFF)) = 0;
    } else {
        int mb = blk - 131;               // 64 MAE blocks, 2484 elems each
        int base = mb * 2484;
        float mk = 0.f, dd = 0.f;
        for (int u = base + t; u < base + 2484; u += 640) {
            float m2 = (uns[u] != 0.f) ? 1.f : 0.f;
            mk += m2;
            dd += fabsf(mu[u] - tg[u]) * m2;
        }
        for (int o = 32; o; o >>= 1) {
            mk += __shfl_down(mk, o, 64);
            dd += __shfl_down(dd, o, 64);
        }
        int wv = t >> 6, l = t & 63;
        if (l == 0) { sh[wv] = mk; sh[16 + wv] = dd; }
        __syncthreads();
        if (t == 0) {
            float a = 0.f, b2 = 0.f;
            for (int q = 0; q < 10; ++q) { a += sh[q]; b2 += sh[16 + q]; }
            ws[MAEC_OFF + mb] = a;
            ws[MAEA_OFF + mb] = b2;
        }
    }
}

// kD: blocked (P=16) Cholesky of A = Dt[c,j]*Ks_c + sig^2 I fused with forward
// substitution for a 32-RHS half. R9: revert SYRK microtile 8x4 -> 4x4 (the 8x4
// accumulator set spilled past the 128-VGPR budget in R8 -> 258 MB scratch);
// keep R8's aligned triangle + b128 RMW writeback (conflicts 5.67M -> 0.55M),
// dead-store elim, and register zacc.
__global__ __launch_bounds__(KDT)
void kD(const float* __restrict__ sig,
        const float* __restrict__ mu,
        const float* __restrict__ tg,
        const float* __restrict__ wgt,
        float* __restrict__ ws,
        float* __restrict__ out) {
    extern __shared__ float lds[];
    float* Apk = lds;                    // TRIP = 22048
    float* W   = Apk + TRIP;             // 32*212 = 6784
    float* Pt  = W + WR*WST;             // 16*244 = 3904
    float* ldg = Pt + 16*PTS;            // 256 (diag block L, row-major)
    float* dnv = ldg + 256;              // 16
    float* utl = dnv + 16;               // 12
    __shared__ int lflag;
    int t = threadIdx.x;
    int bid = blockIdx.x;
    int cj = bid >> 1, hf = bid & 1;     // (c,j) index + RHS half
    int c = cj / TT, jj = cj % TT;
    float dt = ws[DT_OFF + cj];
    float sg = sig[c], sg2 = sg*sg;
    const float* KsC = ws + KS_OFF + (size_t)c*NN*NN;

    if (t < 12) utl[t] = ws[UT_OFF + c*144 + t*12 + jj];
    // stage padded-aligned triangle, one float4 chunk per iteration
    for (int f = t; f < QTOT; f += KDT) {
        int r = (int)((sqrtf(32.f*(float)f + 25.f) - 5.f)*0.5f);
        while ((roff(r+1) >> 2) <= f) ++r;
        while ((roff(r) >> 2) > f) --r;
        int c4 = (f - (roff(r) >> 2)) << 2;
        float4 v;
        float* ve = (float*)&v;
        #pragma unroll
        for (int e = 0; e < 4; ++e) {
            int cc = c4 + e;
            float x;
            if (r == NN) x = (cc == NN) ? 1.f : 0.f;
            else if (cc > r) x = 0.f;
            else { x = dt * KsC[r*NN + cc]; if (cc == r) x += sg2; }
            ve[e] = x;
        }
        *(float4*)(Apk + roff(r) + c4) = v;
    }
    __syncthreads();
    // Y-transform (float4 loads): W[wb][i] = sum_q (tg-mu)[b,i,q]*Ut[c][q][jj]
    for (int u = t; u < WR*NN; u += KDT) {
        int wb = u / NN, i = u - wb*NN;
        int b = hf*WR + wb;
        const float4* mp = (const float4*)(mu + (size_t)(b*NN + i)*TT);
        const float4* tp = (const float4*)(tg + (size_t)(b*NN + i)*TT);
        float4 m0 = mp[0], m1 = mp[1], m2 = mp[2];
        float4 t0 = tp[0], t1 = tp[1], t2 = tp[2];
        float s = (t0.x-m0.x)*utl[0] + (t0.y-m0.y)*utl[1] + (t0.z-m0.z)*utl[2]
                + (t0.w-m0.w)*utl[3] + (t1.x-m1.x)*utl[4] + (t1.y-m1.y)*utl[5]
                + (t1.z-m1.z)*utl[6] + (t1.w-m1.w)*utl[7] + (t2.x-m2.x)*utl[8]
                + (t2.y-m2.y)*utl[9] + (t2.z-m2.z)*utl[10] + (t2.w-m2.w)*utl[11];
        W[wb*WST + i] = s;
    }
    if (t < WR) W[t*WST + NN] = 0.f;
    __syncthreads();

    float zacc = 0.f;                    // per-W-thread ssq accumulator
    for (int p = 0; p < 13; ++p) {
        int k0 = p*16, k1 = k0 + 16;
        int nA = NP - k1;                // <= 192
        // solve-thread roles: A rows t in [0,nA); W rows t in [192,224) (fixed)
        bool isW = (t >= 192 && t < 224);
        bool isA = (t < nA);
        float arow[16];
        int wb = t - 192;
        // ---- preload row-solve operands (b128; overlaps wave0's diag phase)
        if (isA) {
            int abase = roff(k1 + t) + k0;
            float4 a0 = *(const float4*)(Apk + abase);
            float4 a1 = *(const float4*)(Apk + abase + 4);
            float4 a2 = *(const float4*)(Apk + abase + 8);
            float4 a3 = *(const float4*)(Apk + abase + 12);
            arow[0]=a0.x; arow[1]=a0.y; arow[2]=a0.z; arow[3]=a0.w;
            arow[4]=a1.x; arow[5]=a1.y; arow[6]=a1.z; arow[7]=a1.w;
            arow[8]=a2.x; arow[9]=a2.y; arow[10]=a2.z; arow[11]=a2.w;
            arow[12]=a3.x; arow[13]=a3.y; arow[14]=a3.z; arow[15]=a3.w;
        } else if (isW) {
            int wbase = wb*WST + k0;
            float4 a0 = *(const float4*)(W + wbase);
            float4 a1 = *(const float4*)(W + wbase + 4);
            float4 a2 = *(const float4*)(W + wbase + 8);
            float4 a3 = *(const float4*)(W + wbase + 12);
            arow[0]=a0.x; arow[1]=a0.y; arow[2]=a0.z; arow[3]=a0.w;
            arow[4]=a1.x; arow[5]=a1.y; arow[6]=a1.z; arow[7]=a1.w;
            arow[8]=a2.x; arow[9]=a2.y; arow[10]=a2.z; arow[11]=a2.w;
            arow[12]=a3.x; arow[13]=a3.y; arow[14]=a3.z; arow[15]=a3.w;
        }
        // ---- 16x16 diag factor, wave 0, registers + shuffles
        if (t < 64) {
            int r = t;
            int rr = (r < 16) ? (k0 + r) : k0;
            int base = roff(rr) + k0;
            float a[16];
            #pragma unroll
            for (int m = 0; m < 16; ++m) a[m] = Apk[base + m];
            #pragma unroll
            for (int kk = 0; kk < 16; ++kk) {
                float d = __shfl(a[kk], kk);
                float dv = 1.0f / sqrtf(d);
                if (t == 0) dnv[kk] = dv;
                if (r < 16 && r > kk) a[kk] *= dv;
                #pragma unroll
                for (int j2 = kk+1; j2 < 16; ++j2) {
                    float v = __shfl(a[kk], j2);
                    if (r < 16 && r > kk && j2 <= r) a[j2] -= a[kk]*v;
                }
            }
            if (r < 16) {
                #pragma unroll
                for (int m = 0; m < 16; ++m) ldg[r*16 + m] = a[m];
            }
        }
        __syncthreads();
        // ---- unified panel row solve -> Pt only (L-panel/z stores are dead)
        if (isA || isW) {
            #pragma unroll
            for (int kk = 0; kk < 16; ++kk) {
                float x = arow[kk];
                #pragma unroll
                for (int m = 0; m < kk; ++m) x -= arow[m] * ldg[kk*16 + m];
                arow[kk] = x * dnv[kk];
            }
            int rho = isW ? (NP + wb) : (k1 + t);
            if (isW) {
                #pragma unroll
                for (int m = 0; m < 16; ++m) zacc += arow[m]*arow[m];
            }
            #pragma unroll
            for (int m = 0; m < 16; ++m) Pt[m*PTS + rho] = arow[m];
        }
        __syncthreads();
        // ---- trailing rank-16 update, 64x128 tiles, 4x4 microtiles
        int nc2 = NP - k1;
        int nr2 = nc2 + WR;
        if (nc2 > 0) {
            int ty = t >> 5, tx = t & 31;     // 16 x 32 threads
            for (int rg = 0; rg < nr2; rg += 64) {
                int rbase = k1 + rg + 4*ty;
                if (rbase >= NP + WR) continue;
                for (int cg = 0; cg < nc2; cg += 128) {
                    int cbase = k1 + cg + 4*tx;
                    if (cbase >= NP) continue;
                    if (rbase + 3 < cbase && rbase + 3 < NP) continue;
                    float4 acc[4];
                    #pragma unroll
                    for (int a2 = 0; a2 < 4; ++a2) acc[a2] = make_float4(0.f,0.f,0.f,0.f);
                    #pragma unroll
                    for (int kk = 0; kk < 16; ++kk) {
                        const float* pr = Pt + kk*PTS;
                        float4 a0 = *(const float4*)(pr + rbase);
                        float4 bv = *(const float4*)(pr + cbase);
                        acc[0].x += a0.x*bv.x; acc[0].y += a0.x*bv.y;
                        acc[0].z += a0.x*bv.z; acc[0].w += a0.x*bv.w;
                        acc[1].x += a0.y*bv.x; acc[1].y += a0.y*bv.y;
                        acc[1].z += a0.y*bv.z; acc[1].w += a0.y*bv.w;
                        acc[2].x += a0.z*bv.x; acc[2].y += a0.z*bv.y;
                        acc[2].z += a0.z*bv.z; acc[2].w += a0.z*bv.w;
                        acc[3].x += a0.w*bv.x; acc[3].y += a0.w*bv.y;
                        acc[3].z += a0.w*bv.z; acc[3].w += a0.w*bv.w;
                    }
                    int ro = roff(rbase);
                    #pragma unroll
                    for (int ri = 0; ri < 4; ++ri) {
                        int rho = rbase + ri;
                        if (rho >= NP) {                    // W row: full f4 RMW
                            float* wp = W + (rho - NP)*WST + cbase;
                            float4 w = *(float4*)wp;
                            w.x -= acc[ri].x; w.y -= acc[ri].y;
                            w.z -= acc[ri].z; w.w -= acc[ri].w;
                            *(float4*)wp = w;
                        } else if (cbase + 3 <= rho) {      // full f4 RMW in triangle
                            float* ap = Apk + ro + cbase;
                            float4 w = *(float4*)ap;
                            w.x -= acc[ri].x; w.y -= acc[ri].y;
                            w.z -= acc[ri].z; w.w -= acc[ri].w;
                            *(float4*)ap = w;
                        } else if (cbase <= rho) {          // diagonal straddle
                            float* ap = Apk + ro;
                            const float* af = (const float*)&acc[ri];
                            #pragma unroll
                            for (int e = 0; e < 4; ++e) {
                                int jc = cbase + e;
                                if (jc <= rho) ap[jc] -= af[e];
                            }
                        }
                        ro += (rho + 4) & ~3;               // roff(rho+1)
                    }
                }
            }
        }
        __syncthreads();
    }
    // ssq: W threads hold their batch's full ||z||^2 in zacc
    if (t >= 192 && t < 224)
        ws[SSQ_OFF + (cj << 6) + hf*WR + (t - 192)] = zacc;
    // last-block epilogue
    __threadfence();
    __syncthreads();
    if (t == 0) {
        int old = atomicAdd((int*)(ws + CNT_OFF), 1);
        lflag = (old == NBLK - 1) ? 1 : 0;
    }
    __syncthreads();
    if (!lflag) return;
    __threadfence();
    float* ep = Apk;            // reuse LDS: 640 ll values + 64 nll
    float* nl = Apk + 640;
    const float C0 = -0.5f * 2484.0f * 1.8378770664093453f;
    for (int u = t; u < 640; u += KDT) {
        int b2 = u / NC, cc = u % NC;
        float q = 0.f;
        for (int j2 = 0; j2 < TT; ++j2) q += ws[SSQ_OFF + (cc*TT + j2)*64 + b2];
        ep[u] = C0 - 0.5f*q + 207.f*ws[VLOG_OFF + cc] + 12.f*ws[ULOG_OFF + cc]
                + logf(wgt[b2*NC + cc]);
    }
    __syncthreads();
    if (t < 64) {
        float mx = -1e30f;
        for (int cc = 0; cc < NC; ++cc) mx = fmaxf(mx, ep[t*NC + cc]);
        float s = 0.f;
        for (int cc = 0; cc < NC; ++cc) s += expf(ep[t*NC + cc] - mx);
        nl[t] = -(mx + logf(s));
    }
    __syncthreads();
    if (t < 64) {
        float v = nl[t];
        for (int o = 32; o; o >>= 1) v += __shfl_down(v, o, 64);
        if (t == 0) {
            float sm = 0.f, sa = 0.f;
            for (int q2 = 0; q2 < 64; ++q2) {
                sm += ws[MAEC_OFF + q2];
                sa += ws[MAEA_OFF + q2];
            }
            float mse = (sm > 0.f) ? sa / sm : 0.f;
            out[0] = 0.1f * (v * (1.f/64.f)) + 0.9f * mse;
        }
    }
}

extern "C" void kernel_launch(void* const* d_in, const int* in_sizes, int n_in,
                              void* d_out, int out_size, void* d_ws, size_t ws_size,
                              hipStream_t stream) {
    const float* mu  = (const float*)d_in[0];
    const float* tg  = (const float*)d_in[1];
    const float* uns = (const float*)d_in[2];
    const float* wgt = (const float*)d_in[3];
    const float* sig = (const float*)d_in[4];
    // d_in[5] = R, unused by the reference loss
    const float* Ls  = (const float*)d_in[6];
    const float* Lt  = (const float*)d_in[7];
    float* out = (float*)d_out;
    float* ws  = (float*)d_ws;

    const int kd_lds = (TRIP + WR*WST + 16*PTS + 256 + 16 + 12) * 4; // 132,080 B
    (void)hipFuncSetAttribute((const void*)kD,
                              hipFuncAttributeMaxDynamicSharedMemorySize, kd_lds);

    k1<<<195, 640, 0, stream>>>(Ls, Lt, mu, tg, uns, ws);
    kD<<<NBLK, KDT, kd_lds, stream>>>(sig, mu, tg, wgt, ws, out);
}

// Round 10
// 403.171 us; speedup vs baseline: 2.0442x; 1.0461x over previous
//
#include <hip/hip_runtime.h>
#include <math.h>

#define BB 64
#define NN 207
#define TT 12
#define NC 10
#define NP 208              // padded matrix dim (pad row 207: identity)
#define TRIP 22048          // 4-aligned packed lower triangle
#define QTOT 5512           // TRIP/4 quad-chunks for staging
#define WR 32               // RHS rows per block
#define WST 212             // W row stride
#define PTS 244             // Pt row stride
#define KDT 512
#define NBLK 240
#define NKS 910             // k1 Ks tile blocks (10 comps x 91 lower tiles)

// ws layout (float offsets).
#define KS_OFF   0          // [C][N][N]       428490
#define DT_OFF   428490     // [C][T]          120
#define UT_OFF   428610     // [C][T][T]       1440
#define ULOG_OFF 430050
#define VLOG_OFF 430060
#define CNT_OFF  430070
#define MAEC_OFF 430071
#define MAEA_OFF 430135
#define SSQ_OFF  430199     // [C][T][B]       7680

__device__ __forceinline__ int roff(int r) {
    return ((r*(r+1)) >> 1) + 6*(r >> 2) + ((0x6530 >> ((r & 3) << 2)) & 15);
}

__device__ __forceinline__ void WB() {
    __builtin_amdgcn_wave_barrier();
    __asm__ volatile("" ::: "memory");
}

__device__ inline void jpair(int r, int pi, int& p, int& q) {
    if (pi == 0) { p = 11; q = r % 11; }
    else { p = (r + pi) % 11; q = (r + 11 - pi) % 11; }
}

// k1 (256 thr): blocks 0..909: Ks 16x16 output tiles via LDS-staged coalesced
// GEMM (Ls is lower-tri so k-range needs no guards — zeros kill the rest).
// Blocks 910..912: wave-parallel Jacobi (4 comps/block). 913..976: MAE partials.
__global__ __launch_bounds__(256) void k1(const float* __restrict__ Ls,
                                          const float* __restrict__ Lt,
                                          const float* __restrict__ mu,
                                          const float* __restrict__ tg,
                                          const float* __restrict__ uns,
                                          float* __restrict__ ws) {
    __shared__ float sh[1216];
    int t = threadIdx.x;
    int blk = blockIdx.x;
    if (blk < NKS) {
        int c = blk / 91, r = blk % 91;
        int it = (int)((sqrtf(8.f*r + 1.f) - 1.f)*0.5f);
        while ((it+1)*(it+2)/2 <= r) ++it;
        while (it*(it+1)/2 > r) --it;
        int jt = r - it*(it+1)/2;            // jt <= it
        int I0 = it*16, J0 = jt*16;
        float* As = sh;                       // [16][17]
        float* Bs = sh + 272;                 // [16][17]
        int ti = t >> 4, tj = t & 15;
        int srow = t >> 4, skk = t & 15;
        float acc = 0.f;
        for (int kc = 0; kc <= jt; ++kc) {
            int k = kc*16 + skk;
            int ia = I0 + srow, jb = J0 + srow;
            As[srow*17 + skk] = (ia < NN && k < NN) ? Ls[(size_t)(c*NN + ia)*NN + k] : 0.f;
            Bs[srow*17 + skk] = (jb < NN && k < NN) ? Ls[(size_t)(c*NN + jb)*NN + k] : 0.f;
            __syncthreads();
            #pragma unroll
            for (int kk = 0; kk < 16; ++kk)
                acc += As[ti*17 + kk] * Bs[tj*17 + kk];
            __syncthreads();
        }
        int I = I0 + ti, J = J0 + tj;
        if (I < NN && J < NN)
            ws[KS_OFF + (size_t)(c*NN + I)*NN + J] = acc;
    } else if (blk < NKS + 3) {
        int wv = t >> 6, l = t & 63;
        int cb = (blk - NKS)*4 + wv;          // component
        if (cb < NC) {
            float* A  = sh + wv*304;
            float* V  = A + 144;
            float* rc = A + 288;
            float* rs = A + 294;
            for (int u = l; u < 144; u += 64) {
                int i = u / 12, j = u % 12;
                int kmax = (i < j) ? i : j;
                const float* a = Lt + cb*144 + i*12;
                const float* b = Lt + cb*144 + j*12;
                float s = 0.f;
                for (int k = 0; k <= kmax; ++k) s += a[k]*b[k];
                A[u] = s; V[u] = (i == j) ? 1.f : 0.f;
            }
            WB();
            for (int sweep = 0; sweep < 5; ++sweep)
            for (int r = 0; r < 11; ++r) {
                if (l < 6) {
                    int p, q; jpair(r, l, p, q);
                    float app = A[p*13], aqq = A[q*13], apq = A[p*12 + q];
                    float cs = 1.f, sn = 0.f;
                    if (fabsf(apq) > 1e-30f) {
                        float tau = (aqq - app) / (2.f * apq);
                        float t2 = ((tau >= 0.f) ? 1.f : -1.f) / (fabsf(tau) + sqrtf(1.f + tau*tau));
                        cs = 1.f / sqrtf(1.f + t2*t2);
                        sn = t2 * cs;
                    }
                    rc[l] = cs; rs[l] = sn;
                }
                WB();
                for (int u = l; u < 72; u += 64) {
                    int pi = u / 12, k = u % 12, p, q;
                    jpair(r, pi, p, q);
                    float cs = rc[pi], sn = rs[pi];
                    float x = A[p*12 + k], y = A[q*12 + k];
                    A[p*12 + k] = cs*x - sn*y;
                    A[q*12 + k] = sn*x + cs*y;
                }
                WB();
                for (int u = l; u < 144; u += 64) {
                    int isV = (u >= 72);
                    int v2 = isV ? u - 72 : u;
                    int pi = v2 / 12, i = v2 % 12, p, q;
                    jpair(r, pi, p, q);
                    float cs = rc[pi], sn = rs[pi];
                    float* M = isV ? V : A;
                    float x = M[i*12 + p], y = M[i*12 + q];
                    M[i*12 + p] = cs*x - sn*y;
                    M[i*12 + q] = sn*x + cs*y;
                }
                WB();
            }
            if (l < 12) ws[DT_OFF + cb*12 + l] = A[l*13];
            for (int u = l; u < 144; u += 64) ws[UT_OFF + cb*144 + u] = V[u];
            float su = 0.f;
            for (int i = l; i < NN; i += 64) su += logf(Ls[(size_t)(cb*NN + i)*NN + i]);
            for (int o = 32; o; o >>= 1) su += __shfl_down(su, o, 64);
            if (l == 0) ws[ULOG_OFF + cb] = su;
            float sv = (l < 12) ? logf(Lt[cb*144 + l*13]) : 0.f;
            for (int o = 32; o; o >>= 1) sv += __shfl_down(sv, o, 64);
            if (l == 0) ws[VLOG_OFF + cb] = sv;
        }
        if (blk == NKS && t == 0) *((int*)(ws + CNT_OFF)) = 0;
    } else {
        int mb = blk - (NKS + 3);             // 64 MAE blocks
        int base = mb * 2484;
        float mk = 0.f, dd = 0.f;
        for (int u = base + t; u < base + 2484; u += 256) {
            float m2 = (uns[u] != 0.f) ? 1.f : 0.f;
            mk += m2;
            dd += fabsf(mu[u] - tg[u]) * m2;
        }
        for (int o = 32; o; o >>= 1) {
            mk += __shfl_down(mk, o, 64);
            dd += __shfl_down(dd, o, 64);
        }
        int wv = t >> 6, l = t & 63;
        if (l == 0) { sh[wv] = mk; sh[16 + wv] = dd; }
        __syncthreads();
        if (t == 0) {
            float a = 0.f, b2 = 0.f;
            for (int q = 0; q < 4; ++q) { a += sh[q]; b2 += sh[16 + q]; }
            ws[MAEC_OFF + mb] = a;
            ws[MAEA_OFF + mb] = b2;
        }
    }
}

// kD R10: software-pipelined panel loop.
//  - S1: 32-col SYRK slice finalizing panel p+1's diag & solve columns
//    (col-block m receives S1(m-1)+S1(m-2)+S2(p<=m-3): each panel once)
//  - combined phase: wave0 factors next diag WHILE waves 1-7 run bulk S2
//    and solve threads preload next arow (diag latency off critical path)
//  - solve reads ldg rows as float4 (R9: 136 dependent b32 broadcast reads
//    serialized at LDS latency = the dominant stall)
__global__ __launch_bounds__(KDT)
void kD(const float* __restrict__ sig,
        const float* __restrict__ mu,
        const float* __restrict__ tg,
        const float* __restrict__ wgt,
        float* __restrict__ ws,
        float* __restrict__ out) {
    extern __shared__ float lds[];
    float* Apk = lds;                    // TRIP
    float* W   = Apk + TRIP;             // 32*212
    float* Pt  = W + WR*WST;             // 16*244
    float* ldg = Pt + 16*PTS;            // 256
    float* dnv = ldg + 256;              // 16
    float* utl = dnv + 16;               // 12
    __shared__ int lflag;
    int t = threadIdx.x;
    int bid = blockIdx.x;
    int cj = bid >> 1, hf = bid & 1;
    int c = cj / TT, jj = cj % TT;
    float dt = ws[DT_OFF + cj];
    float sg = sig[c], sg2 = sg*sg;
    const float* KsC = ws + KS_OFF + (size_t)c*NN*NN;

    if (t < 12) utl[t] = ws[UT_OFF + c*144 + t*12 + jj];
    for (int f = t; f < QTOT; f += KDT) {
        int r = (int)((sqrtf(32.f*(float)f + 25.f) - 5.f)*0.5f);
        while ((roff(r+1) >> 2) <= f) ++r;
        while ((roff(r) >> 2) > f) --r;
        int c4 = (f - (roff(r) >> 2)) << 2;
        float4 v;
        float* ve = (float*)&v;
        #pragma unroll
        for (int e = 0; e < 4; ++e) {
            int cc = c4 + e;
            float x;
            if (r == NN) x = (cc == NN) ? 1.f : 0.f;
            else if (cc > r) x = 0.f;
            else { x = dt * KsC[r*NN + cc]; if (cc == r) x += sg2; }
            ve[e] = x;
        }
        *(float4*)(Apk + roff(r) + c4) = v;
    }
    __syncthreads();
    for (int u = t; u < WR*NN; u += KDT) {
        int wb2 = u / NN, i = u - wb2*NN;
        int b = hf*WR + wb2;
        const float4* mp = (const float4*)(mu + (size_t)(b*NN + i)*TT);
        const float4* tp = (const float4*)(tg + (size_t)(b*NN + i)*TT);
        float4 m0 = mp[0], m1 = mp[1], m2 = mp[2];
        float4 t0 = tp[0], t1 = tp[1], t2 = tp[2];
        float s = (t0.x-m0.x)*utl[0] + (t0.y-m0.y)*utl[1] + (t0.z-m0.z)*utl[2]
                + (t0.w-m0.w)*utl[3] + (t1.x-m1.x)*utl[4] + (t1.y-m1.y)*utl[5]
                + (t1.z-m1.z)*utl[6] + (t1.w-m1.w)*utl[7] + (t2.x-m2.x)*utl[8]
                + (t2.y-m2.y)*utl[9] + (t2.z-m2.z)*utl[10] + (t2.w-m2.w)*utl[11];
        W[wb2*WST + i] = s;
    }
    if (t < WR) W[t*WST + NN] = 0.f;
    __syncthreads();

    int wb = t - 192;
    float arow[16];

    auto preload = [&](int k0n) {            // k0n = panel base col
        int k1n = k0n + 16;
        int nA = NP - k1n;
        if (t < nA) {
            int abase = roff(k1n + t) + k0n;
            *(float4*)(arow+0)  = *(const float4*)(Apk + abase);
            *(float4*)(arow+4)  = *(const float4*)(Apk + abase + 4);
            *(float4*)(arow+8)  = *(const float4*)(Apk + abase + 8);
            *(float4*)(arow+12) = *(const float4*)(Apk + abase + 12);
        } else if (t >= 192 && t < 224) {
            int wbase = wb*WST + k0n;
            *(float4*)(arow+0)  = *(const float4*)(W + wbase);
            *(float4*)(arow+4)  = *(const float4*)(W + wbase + 4);
            *(float4*)(arow+8)  = *(const float4*)(W + wbase + 8);
            *(float4*)(arow+12) = *(const float4*)(W + wbase + 12);
        }
    };
    auto diagf = [&](int kd0) {              // wave0 only (t<64)
        int r = t;
        int rr = (r < 16) ? (kd0 + r) : kd0;
        int base = roff(rr) + kd0;
        float a[16];
        #pragma unroll
        for (int m = 0; m < 16; ++m) a[m] = Apk[base + m];
        #pragma unroll
        for (int kk = 0; kk < 16; ++kk) {
            float d = __shfl(a[kk], kk);
            float dv = 1.0f / sqrtf(d);
            if (t == 0) dnv[kk] = dv;
            if (r < 16 && r > kk) a[kk] *= dv;
            #pragma unroll
            for (int j2 = kk+1; j2 < 16; ++j2) {
                float v = __shfl(a[kk], j2);
                if (r < 16 && r > kk && j2 <= r) a[j2] -= a[kk]*v;
            }
        }
        if (r < 16) {
            #pragma unroll
            for (int m = 0; m < 16; ++m) ldg[r*16 + m] = a[m];
        }
    };
    auto tile44 = [&](int rbase, int cbase) {
        float4 acc0 = make_float4(0.f,0.f,0.f,0.f);
        float4 acc1 = acc0, acc2 = acc0, acc3 = acc0;
        #pragma unroll
        for (int kk = 0; kk < 16; ++kk) {
            const float* pr = Pt + kk*PTS;
            float4 a0 = *(const float4*)(pr + rbase);
            float4 bv = *(const float4*)(pr + cbase);
            acc0.x += a0.x*bv.x; acc0.y += a0.x*bv.y; acc0.z += a0.x*bv.z; acc0.w += a0.x*bv.w;
            acc1.x += a0.y*bv.x; acc1.y += a0.y*bv.y; acc1.z += a0.y*bv.z; acc1.w += a0.y*bv.w;
            acc2.x += a0.z*bv.x; acc2.y += a0.z*bv.y; acc2.z += a0.z*bv.z; acc2.w += a0.z*bv.w;
            acc3.x += a0.w*bv.x; acc3.y += a0.w*bv.y; acc3.z += a0.w*bv.z; acc3.w += a0.w*bv.w;
        }
        float4 accs[4] = {acc0, acc1, acc2, acc3};
        int ro = roff(rbase);
        #pragma unroll
        for (int ri = 0; ri < 4; ++ri) {
            int rho = rbase + ri;
            if (rho >= NP) {
                float* wp = W + (rho - NP)*WST + cbase;
                float4 w = *(float4*)wp;
                w.x -= accs[ri].x; w.y -= accs[ri].y; w.z -= accs[ri].z; w.w -= accs[ri].w;
                *(float4*)wp = w;
            } else if (cbase + 3 <= rho) {
                float* ap = Apk + ro + cbase;
                float4 w = *(float4*)ap;
                w.x -= accs[ri].x; w.y -= accs[ri].y; w.z -= accs[ri].z; w.w -= accs[ri].w;
                *(float4*)ap = w;
            } else if (cbase <= rho) {
                float* ap = Apk + ro;
                const float* af = (const float*)&accs[ri];
                #pragma unroll
                for (int e = 0; e < 4; ++e) {
                    int jc = cbase + e;
                    if (jc <= rho) ap[jc] -= af[e];
                }
            }
            ro += (rho + 4) & ~3;
        }
    };

    // initial: preload(0) + diag(0)
    preload(0);
    if (t < 64) diagf(0);
    __syncthreads();

    float zacc = 0.f;
    for (int p = 0; p < 13; ++p) {
        int k0v = p*16, k1v = k0v + 16;
        int nA = NP - k1v;
        bool isA = (t < nA), isW = (t >= 192 && t < 224);
        // ---- solve(p): uses preloaded arow + ldg/dnv; f4 row loads pipeline
        if (isA || isW) {
            float dnvr[16];
            *(float4*)(dnvr+0)  = *(const float4*)(dnv+0);
            *(float4*)(dnvr+4)  = *(const float4*)(dnv+4);
            *(float4*)(dnvr+8)  = *(const float4*)(dnv+8);
            *(float4*)(dnvr+12) = *(const float4*)(dnv+12);
            #pragma unroll
            for (int kk = 0; kk < 16; ++kk) {
                float lr[16];
                *(float4*)(lr+0)  = *(const float4*)(ldg + kk*16);
                *(float4*)(lr+4)  = *(const float4*)(ldg + kk*16 + 4);
                *(float4*)(lr+8)  = *(const float4*)(ldg + kk*16 + 8);
                *(float4*)(lr+12) = *(const float4*)(ldg + kk*16 + 12);
                float x = arow[kk];
                #pragma unroll
                for (int m = 0; m < kk; ++m) x -= arow[m] * lr[m];
                arow[kk] = x * dnvr[kk];
            }
            int rho = isW ? (NP + wb) : (k1v + t);
            if (isW) {
                #pragma unroll
                for (int m = 0; m < 16; ++m) zacc += arow[m]*arow[m];
            }
            #pragma unroll
            for (int m = 0; m < 16; ++m) Pt[m*PTS + rho] = arow[m];
        }
        __syncthreads();
        if (p < 12) {
            // ---- S1: cols [k1v, k1v+32), all rows (finalizes next panel cols)
            {
                int tx8 = t & 7, ty64 = t >> 3;
                int rbase = k1v + 4*ty64;
                int cbase = k1v + 4*tx8;
                if (rbase < NP + WR && cbase < NP && !(rbase + 3 < cbase))
                    tile44(rbase, cbase);
            }
            __syncthreads();
            // ---- combined: preload(p+1); wave0: diag(p+1); waves 1-7: S2(p)
            preload(k1v);
            if (t < 64) {
                diagf(k1v);
            } else {
                int ty7 = (t - 64) >> 5, tx = t & 31;
                int ncol = NP - k1v - 32;
                for (int rg = 0; rg < 224; rg += 56) {
                    int rbase = k1v + rg + 4*ty7;
                    if (rbase >= NP + WR) continue;
                    for (int cg = 0; cg < ncol; cg += 128) {
                        int cbase = k1v + 32 + cg + 4*tx;
                        if (cbase >= NP) continue;
                        if (rbase + 3 < cbase) continue;
                        tile44(rbase, cbase);
                    }
                }
            }
            __syncthreads();
        }
    }
    if (t >= 192 && t < 224)
        ws[SSQ_OFF + (cj << 6) + hf*WR + wb] = zacc;
    // last-block epilogue
    __threadfence();
    __syncthreads();
    if (t == 0) {
        int old = atomicAdd((int*)(ws + CNT_OFF), 1);
        lflag = (old == NBLK - 1) ? 1 : 0;
    }
    __syncthreads();
    if (!lflag) return;
    __threadfence();
    float* ep = Apk;
    float* nl = Apk + 640;
    const float C0 = -0.5f * 2484.0f * 1.8378770664093453f;
    for (int u = t; u < 640; u += KDT) {
        int b2 = u / NC, cc = u % NC;
        float q = 0.f;
        for (int j2 = 0; j2 < TT; ++j2) q += ws[SSQ_OFF + (cc*TT + j2)*64 + b2];
        ep[u] = C0 - 0.5f*q + 207.f*ws[VLOG_OFF + cc] + 12.f*ws[ULOG_OFF + cc]
                + logf(wgt[b2*NC + cc]);
    }
    __syncthreads();
    if (t < 64) {
        float mx = -1e30f;
        for (int cc = 0; cc < NC; ++cc) mx = fmaxf(mx, ep[t*NC + cc]);
        float s = 0.f;
        for (int cc = 0; cc < NC; ++cc) s += expf(ep[t*NC + cc] - mx);
        nl[t] = -(mx + logf(s));
    }
    __syncthreads();
    if (t < 64) {
        float v = nl[t];
        for (int o = 32; o; o >>= 1) v += __shfl_down(v, o, 64);
        if (t == 0) {
            float sm = 0.f, sa = 0.f;
            for (int q2 = 0; q2 < 64; ++q2) {
                sm += ws[MAEC_OFF + q2];
                sa += ws[MAEA_OFF + q2];
            }
            float mse = (sm > 0.f) ? sa / sm : 0.f;
            out[0] = 0.1f * (v * (1.f/64.f)) + 0.9f * mse;
        }
    }
}

extern "C" void kernel_launch(void* const* d_in, const int* in_sizes, int n_in,
                              void* d_out, int out_size, void* d_ws, size_t ws_size,
                              hipStream_t stream) {
    const float* mu  = (const float*)d_in[0];
    const float* tg  = (const float*)d_in[1];
    const float* uns = (const float*)d_in[2];
    const float* wgt = (const float*)d_in[3];
    const float* sig = (const float*)d_in[4];
    const float* Ls  = (const float*)d_in[6];
    const float* Lt  = (const float*)d_in[7];
    float* out = (float*)d_out;
    float* ws  = (float*)d_ws;

    const int kd_lds = (TRIP + WR*WST + 16*PTS + 256 + 16 + 12) * 4; // 132,080 B
    (void)hipFuncSetAttribute((const void*)kD,
                              hipFuncAttributeMaxDynamicSharedMemorySize, kd_lds);

    k1<<<NKS + 3 + 64, 256, 0, stream>>>(Ls, Lt, mu, tg, uns, ws);
    kD<<<NBLK, KDT, kd_lds, stream>>>(sig, mu, tg, wgt, ws, out);
}